// Round 1
// baseline (1611.675 us; speedup 1.0000x reference)
//
#include <hip/hip_runtime.h>
#include <math.h>

// ---------------------------------------------------------------------------
// GenNet_tanh forward: FEM -> batched GNN -> 4-step IGRU + attentive align ->
// EAM heads -> pairwise tanh decoder.  All f32.  Round 1: correctness-first.
// ---------------------------------------------------------------------------

#define T_WIN 4
#define NN 2048
#define F_IN 128
#define HF 256
#define HH 256      // H
#define DZ 128
#define G_IN 384    // HF + DZ
#define EIN 512     // H + HF
#define E1D 256
#define E2D 64

__device__ __forceinline__ float wave_sum(float v) {
#pragma unroll
  for (int o = 32; o > 0; o >>= 1) v += __shfl_down(v, o);
  return v;
}
__device__ __forceinline__ float wave_max(float v) {
#pragma unroll
  for (int o = 32; o > 0; o >>= 1) v = fmaxf(v, __shfl_down(v, o));
  return v;
}

// ---------------------------------------------------------------------------
// Tiled f32 GEMM: C[M,N] = epi( A_eff @ B (+bias) (+C) )
//   A: [M,K] row-major.  B: [K,N] row-major, or TRANSB: B: [N,K] row-major.
//   MIX: A_eff = lam*A + (1-lam)*A2 (lam loaded from device scalar).
//   EPI: 0 none, 1 relu, 2 sigmoid, 3 tanh.  ACC: add existing C before epi.
//   Block tile 64x64, K-tile 16, 256 threads, 4x4 per thread.
//   All M,N,K used here are multiples of 64/16 -> no bounds checks.
// ---------------------------------------------------------------------------
template <int EPI, bool ACC, bool TRANSB, bool MIX>
__global__ __launch_bounds__(256) void gemm_f32(
    const float* __restrict__ A, const float* __restrict__ A2,
    const float* __restrict__ lam_ptr, const float* __restrict__ B,
    const float* __restrict__ bias, float* __restrict__ C, int M, int N, int K,
    long sA, long sB, long sC) {
  __shared__ float As[16][68];
  __shared__ float Bs[16][68];
  const int tid = threadIdx.x;
  const int tx = tid & 15, ty = tid >> 4;
  const int row0 = blockIdx.y * 64, col0 = blockIdx.x * 64;
  const long zb = blockIdx.z;
  const float* Ab = A + zb * sA;
  const float* Bb = B + zb * sB;
  float* Cb = C + zb * sC;
  float lam = 0.f, oml = 0.f;
  if (MIX) {
    lam = lam_ptr[0];
    oml = 1.f - lam;
  }

  float acc[4][4] = {};

  const int lka = tid & 15, lma = tid >> 4;  // A / B^T staging
  const int lnb = tid & 63, lkb = tid >> 6;  // B staging

  for (int k0 = 0; k0 < K; k0 += 16) {
#pragma unroll
    for (int p = 0; p < 4; ++p) {
      int m = lma + 16 * p;
      long gi = (long)(row0 + m) * K + k0 + lka;
      float v = Ab[gi];
      if (MIX) v = lam * v + oml * A2[gi];
      As[lka][m] = v;
    }
    if (TRANSB) {
#pragma unroll
      for (int p = 0; p < 4; ++p) {
        int j = lma + 16 * p;
        Bs[lka][j] = Bb[(long)(col0 + j) * K + k0 + lka];
      }
    } else {
#pragma unroll
      for (int p = 0; p < 4; ++p) {
        int kk = lkb + 4 * p;
        Bs[kk][lnb] = Bb[(long)(k0 + kk) * N + col0 + lnb];
      }
    }
    __syncthreads();
#pragma unroll
    for (int kk = 0; kk < 16; ++kk) {
      float4 av = *reinterpret_cast<const float4*>(&As[kk][ty * 4]);
      float4 bv = *reinterpret_cast<const float4*>(&Bs[kk][tx * 4]);
      float a4[4] = {av.x, av.y, av.z, av.w};
      float b4[4] = {bv.x, bv.y, bv.z, bv.w};
#pragma unroll
      for (int i = 0; i < 4; ++i)
#pragma unroll
        for (int j = 0; j < 4; ++j) acc[i][j] = fmaf(a4[i], b4[j], acc[i][j]);
    }
    __syncthreads();
  }

#pragma unroll
  for (int i = 0; i < 4; ++i) {
    long r = row0 + ty * 4 + i;
#pragma unroll
    for (int j = 0; j < 4; ++j) {
      int cc = col0 + tx * 4 + j;
      float v = acc[i][j];
      if (bias) v += bias[cc];
      if (ACC) v += Cb[r * N + cc];
      if (EPI == 1) v = fmaxf(v, 0.f);
      if (EPI == 2) v = 1.f / (1.f + __expf(-v));
      if (EPI == 3) v = tanhf(v);
      Cb[r * N + cc] = v;
    }
  }
}

// --- row-wise L2 norm for 256-wide rows (GNN output) ------------------------
__global__ __launch_bounds__(256) void row_l2norm_256(float* __restrict__ x) {
  const int tid = threadIdx.x;
  float* p = x + (long)blockIdx.x * 256;
  float v = p[tid];
  __shared__ float red[4];
  float w = wave_sum(v * v);
  if ((tid & 63) == 0) red[tid >> 6] = w;
  __syncthreads();
  float tot = red[0] + red[1] + red[2] + red[3];
  p[tid] = v / fmaxf(sqrtf(tot), 1e-12f);
}

// --- row softmax over 2048 columns ------------------------------------------
__global__ __launch_bounds__(256) void softmax_row2048(float* __restrict__ S) {
  const int tid = threadIdx.x;
  float* p = S + (long)blockIdx.x * 2048;
  float4* p4 = reinterpret_cast<float4*>(p);
  float4 a = p4[tid], b = p4[tid + 256];
  float m = fmaxf(fmaxf(fmaxf(a.x, a.y), fmaxf(a.z, a.w)),
                  fmaxf(fmaxf(b.x, b.y), fmaxf(b.z, b.w)));
  __shared__ float red[4];
  float w = wave_max(m);
  if ((tid & 63) == 0) red[tid >> 6] = w;
  __syncthreads();
  m = fmaxf(fmaxf(red[0], red[1]), fmaxf(red[2], red[3]));
  __syncthreads();
  a.x = __expf(a.x - m); a.y = __expf(a.y - m);
  a.z = __expf(a.z - m); a.w = __expf(a.w - m);
  b.x = __expf(b.x - m); b.y = __expf(b.y - m);
  b.z = __expf(b.z - m); b.w = __expf(b.w - m);
  float s = a.x + a.y + a.z + a.w + b.x + b.y + b.z + b.w;
  w = wave_sum(s);
  if ((tid & 63) == 0) red[tid >> 6] = w;
  __syncthreads();
  float inv = 1.f / (red[0] + red[1] + red[2] + red[3]);
  a.x *= inv; a.y *= inv; a.z *= inv; a.w *= inv;
  b.x *= inv; b.y *= inv; b.z *= inv; b.w *= inv;
  p4[tid] = a;
  p4[tid + 256] = b;
}

// --- concat [fem_t | noise_t] -> edm [T,N,384] -------------------------------
__global__ __launch_bounds__(256) void concat_edm(
    const float* __restrict__ fem, const float* __restrict__ noise,
    float* __restrict__ edm) {
  int idx = blockIdx.x * 256 + threadIdx.x;  // T_WIN*NN*G_IN
  int tn = idx / G_IN, f = idx % G_IN;
  edm[idx] = (f < HF) ? fem[tn * HF + f] : noise[tn * DZ + (f - HF)];
}

// --- concat [h | fem_T] -> ecat [N,512] --------------------------------------
__global__ __launch_bounds__(256) void concat_ecat(
    const float* __restrict__ h, const float* __restrict__ fem4,
    float* __restrict__ ecat) {
  int idx = blockIdx.x * 256 + threadIdx.x;  // NN*EIN
  int n = idx >> 9, f = idx & 511;
  ecat[idx] = (f < HH) ? h[n * HH + f] : fem4[n * HF + (f - HH)];
}

// --- rh = r * h  (r = gates[:, :256]) ---------------------------------------
__global__ __launch_bounds__(256) void rh_mul(const float* __restrict__ gates,
                                              const float* __restrict__ h,
                                              float* __restrict__ rh) {
  int idx = blockIdx.x * 256 + threadIdx.x;  // NN*HH
  int n = idx >> 8, k = idx & 255;
  rh[idx] = gates[n * 512 + k] * h[idx];
}

// --- rnn = (1-u)*h + u*c  (u = gates[:, 256:]) -------------------------------
__global__ __launch_bounds__(256) void rnn_mix(const float* __restrict__ gates,
                                               const float* __restrict__ h,
                                               const float* __restrict__ c,
                                               float* __restrict__ rnn) {
  int idx = blockIdx.x * 256 + threadIdx.x;
  int n = idx >> 8, k = idx & 255;
  float u = gates[n * 512 + 256 + k];
  rnn[idx] = (1.f - u) * h[idx] + u * c[idx];
}

// --- column L2 norms of emb0 [N,64] ------------------------------------------
__global__ __launch_bounds__(256) void col_l2norm64(const float* __restrict__ x,
                                                    float* __restrict__ cn) {
  int c = blockIdx.x;
  float ss = 0.f;
  for (int r = threadIdx.x; r < NN; r += 256) {
    float v = x[(long)r * 64 + c];
    ss += v * v;
  }
  __shared__ float red[4];
  float w = wave_sum(ss);
  if ((threadIdx.x & 63) == 0) red[threadIdx.x >> 6] = w;
  __syncthreads();
  if (threadIdx.x == 0)
    cn[c] = fmaxf(sqrtf(red[0] + red[1] + red[2] + red[3]), 1e-12f);
}

// --- emb = emb0 / cn ; sq[i] = sum_j emb[i,j]^2 ------------------------------
__global__ void norm_sq64(const float* __restrict__ x,
                          const float* __restrict__ cn, float* __restrict__ emb,
                          float* __restrict__ sq) {
  int i = blockIdx.x, j = threadIdx.x;  // 64 threads = 1 wave
  float e = x[(long)i * 64 + j] / cn[j];
  emb[(long)i * 64 + j] = e;
  float s = wave_sum(e * e);
  if (j == 0) sq[i] = s;
}

// --- out = 1 + tanh(-(sq_i + sq_j - 2 P) * Q) --------------------------------
__global__ __launch_bounds__(256) void final_decode(
    const float* __restrict__ P, const float* __restrict__ Q,
    const float* __restrict__ sq, float* __restrict__ out) {
  int idx = blockIdx.x * 256 + threadIdx.x;
  int i = idx >> 11, j = idx & 2047;
  float dist = -(sq[i] + sq[j] - 2.f * P[idx]);
  out[idx] = 1.f + tanhf(dist * Q[idx]);
}

// ---------------------------------------------------------------------------
extern "C" void kernel_launch(void* const* d_in, const int* in_sizes, int n_in,
                              void* d_out, int out_size, void* d_ws,
                              size_t ws_size, hipStream_t stream) {
  (void)in_sizes; (void)n_in; (void)out_size; (void)ws_size;
  const float* sup    = (const float*)d_in[0];
  const float* feat   = (const float*)d_in[1];
  const float* noise  = (const float*)d_in[2];
  const float* align  = (const float*)d_in[3];
  const float* lambd  = (const float*)d_in[4];
  const float* W_fem  = (const float*)d_in[5];
  const float* b_fem  = (const float*)d_in[6];
  const float* W_gnn  = (const float*)d_in[7];
  const float* b_gnn  = (const float*)d_in[8];
  const float* Wg_x   = (const float*)d_in[9];
  const float* Wg_h   = (const float*)d_in[10];
  const float* bg     = (const float*)d_in[11];
  const float* Wc_x   = (const float*)d_in[12];
  const float* Wc_h   = (const float*)d_in[13];
  const float* bc     = (const float*)d_in[14];
  const float* W_att  = (const float*)d_in[15];
  const float* b_att  = (const float*)d_in[16];
  const float* W_emb1 = (const float*)d_in[17];
  const float* b_emb1 = (const float*)d_in[18];
  const float* W_emb2 = (const float*)d_in[19];
  const float* b_emb2 = (const float*)d_in[20];
  const float* W_scal1= (const float*)d_in[21];
  const float* b_scal1= (const float*)d_in[22];
  const float* W_scal2= (const float*)d_in[23];
  const float* b_scal2= (const float*)d_in[24];

  float* ws = (float*)d_ws;
  long off = 0;
  auto alloc = [&](long n) { float* p = ws + off; off += n; return p; };
  float* fem   = alloc(5L * NN * HF);      // [5,N,256]
  float* fmb   = alloc(5L * NN * HH);      // [5,N,256]
  float* edm   = alloc((long)T_WIN * NN * G_IN);  // [4,N,384]
  float* agg   = alloc((long)T_WIN * NN * G_IN);  // [4,N,384]
  float* gbuf  = alloc((long)T_WIN * NN * HH);    // [4,N,256]
  float* hbuf  = alloc((long)NN * HH);
  float* h2buf = alloc((long)NN * HH);
  float* gates = alloc((long)NN * 512);
  float* rhb   = alloc((long)NN * HH);
  float* cbuf  = alloc((long)NN * HH);
  float* rnnb  = alloc((long)NN * HH);
  float* Sbuf  = alloc((long)NN * NN);     // scores; reused as P at the end
  float* ecat  = alloc((long)NN * EIN);
  float* e1    = alloc((long)NN * E1D);
  float* emb0  = alloc((long)NN * E2D);
  float* emb   = alloc((long)NN * E2D);
  float* s1    = alloc((long)NN * E1D);
  float* scal  = alloc((long)NN * E2D);
  float* cn    = alloc(64);
  float* sq    = alloc(NN);
  float* Qbuf  = edm;  // edm+agg region (6.3M floats) is free after GNN; Q needs 4.2M

  const float* NO = nullptr;

  // --- FEM: fem = relu(feat @ W_fem + b_fem), all 5 snapshots at once --------
  gemm_f32<1, false, false, false><<<dim3(HF / 64, 5 * NN / 64, 1), 256, 0, stream>>>(
      feat, NO, NO, W_fem, b_fem, fem, 5 * NN, HF, F_IN, 0, 0, 0);

  // --- edm = concat(fem[:4], noise) ------------------------------------------
  concat_edm<<<(T_WIN * NN * G_IN) / 256, 256, 0, stream>>>(fem, noise, edm);

  // --- agg[t] = sup[t] @ edm[t]  (batched over t) -----------------------------
  gemm_f32<0, false, false, false><<<dim3(G_IN / 64, NN / 64, T_WIN), 256, 0, stream>>>(
      sup, NO, NO, edm, NO, agg, NN, G_IN, NN,
      (long)NN * NN, (long)NN * G_IN, (long)NN * G_IN);

  // --- g = l2norm(relu(agg @ W_gnn + b_gnn)) ---------------------------------
  gemm_f32<1, false, false, false><<<dim3(HH / 64, NN / 64, T_WIN), 256, 0, stream>>>(
      agg, NO, NO, W_gnn, b_gnn, gbuf, NN, HH, G_IN,
      (long)NN * G_IN, 0, (long)NN * HH);
  row_l2norm_256<<<T_WIN * NN, 256, 0, stream>>>(gbuf);

  // --- fm = fem @ W_att + b_att (batched over 5) ------------------------------
  gemm_f32<0, false, false, false><<<dim3(HH / 64, NN / 64, 5), 256, 0, stream>>>(
      fem, NO, NO, W_att, b_att, fmb, NN, HH, HF,
      (long)NN * HF, 0, (long)NN * HH);

  // --- scan --------------------------------------------------------------------
  hipMemsetAsync(hbuf, 0, (long)NN * HH * sizeof(float), stream);
  float* hcur = hbuf;
  float* hnext = h2buf;
  for (int t = 0; t < T_WIN; ++t) {
    const float* gt = gbuf + (long)t * NN * HH;
    // gates = sigmoid(gt @ Wg_x + h @ Wg_h + bg)
    gemm_f32<0, false, false, false><<<dim3(512 / 64, NN / 64, 1), 256, 0, stream>>>(
        gt, NO, NO, Wg_x, NO, gates, NN, 512, HH, 0, 0, 0);
    gemm_f32<2, true, false, false><<<dim3(512 / 64, NN / 64, 1), 256, 0, stream>>>(
        hcur, NO, NO, Wg_h, bg, gates, NN, 512, HH, 0, 0, 0);
    // rh = r * h
    rh_mul<<<(NN * HH) / 256, 256, 0, stream>>>(gates, hcur, rhb);
    // c = tanh(gt @ Wc_x + rh @ Wc_h + bc)
    gemm_f32<0, false, false, false><<<dim3(HH / 64, NN / 64, 1), 256, 0, stream>>>(
        gt, NO, NO, Wc_x, NO, cbuf, NN, HH, HH, 0, 0, 0);
    gemm_f32<3, true, false, false><<<dim3(HH / 64, NN / 64, 1), 256, 0, stream>>>(
        rhb, NO, NO, Wc_h, bc, cbuf, NN, HH, HH, 0, 0, 0);
    // rnn = (1-u)*h + u*c
    rnn_mix<<<(NN * HH) / 256, 256, 0, stream>>>(gates, hcur, cbuf, rnnb);
    // S = fm[t+1] @ fm[t]^T ; softmax rows
    gemm_f32<0, false, true, false><<<dim3(NN / 64, NN / 64, 1), 256, 0, stream>>>(
        fmb + (long)(t + 1) * NN * HH, NO, NO, fmb + (long)t * NN * HH, NO,
        Sbuf, NN, NN, HH, 0, 0, 0);
    softmax_row2048<<<NN, 256, 0, stream>>>(Sbuf);
    // h_new = (lam*align[t] + (1-lam)*S) @ rnn
    gemm_f32<0, false, false, true><<<dim3(HH / 64, NN / 64, 1), 256, 0, stream>>>(
        align + (long)t * NN * NN, Sbuf, lambd, rnnb, NO, hnext, NN, HH, NN,
        0, 0, 0);
    float* tmp = hcur; hcur = hnext; hnext = tmp;
  }

  // --- EAM ----------------------------------------------------------------------
  concat_ecat<<<(NN * EIN) / 256, 256, 0, stream>>>(
      hcur, fem + 4L * NN * HF, ecat);
  gemm_f32<3, false, false, false><<<dim3(E1D / 64, NN / 64, 1), 256, 0, stream>>>(
      ecat, NO, NO, W_emb1, b_emb1, e1, NN, E1D, EIN, 0, 0, 0);
  gemm_f32<3, false, false, false><<<dim3(E2D / 64, NN / 64, 1), 256, 0, stream>>>(
      e1, NO, NO, W_emb2, b_emb2, emb0, NN, E2D, E1D, 0, 0, 0);
  col_l2norm64<<<64, 256, 0, stream>>>(emb0, cn);
  norm_sq64<<<NN, 64, 0, stream>>>(emb0, cn, emb, sq);
  gemm_f32<2, false, false, false><<<dim3(E1D / 64, NN / 64, 1), 256, 0, stream>>>(
      ecat, NO, NO, W_scal1, b_scal1, s1, NN, E1D, EIN, 0, 0, 0);
  gemm_f32<2, false, false, false><<<dim3(E2D / 64, NN / 64, 1), 256, 0, stream>>>(
      s1, NO, NO, W_scal2, b_scal2, scal, NN, E2D, E1D, 0, 0, 0);

  // P = emb @ emb^T (into Sbuf), Q = scal @ scal^T (into Qbuf)
  gemm_f32<0, false, true, false><<<dim3(NN / 64, NN / 64, 1), 256, 0, stream>>>(
      emb, NO, NO, emb, NO, Sbuf, NN, NN, E2D, 0, 0, 0);
  gemm_f32<0, false, true, false><<<dim3(NN / 64, NN / 64, 1), 256, 0, stream>>>(
      scal, NO, NO, scal, NO, Qbuf, NN, NN, E2D, 0, 0, 0);

  final_decode<<<(NN * NN) / 256, 256, 0, stream>>>(Sbuf, Qbuf, sq,
                                                    (float*)d_out);
}

// Round 2
// 586.340 us; speedup vs baseline: 2.7487x; 2.7487x over previous
//
#include <hip/hip_runtime.h>
#include <math.h>

// ---------------------------------------------------------------------------
// GenNet_tanh forward, round 2: all GEMMs -> fp16 MFMA (16x16x32_f16),
// m97-style 128xBN tiles with global_load_lds staging. f32 accumulate.
// ---------------------------------------------------------------------------

#define T_WIN 4
#define NN 2048
#define F_IN 128
#define HF 256
#define HH 256
#define DZ 128
#define G_IN 384
#define EIN 512
#define E1D 256
#define E2D 64

typedef _Float16 f16;
typedef _Float16 f16x8 __attribute__((ext_vector_type(8)));
typedef _Float16 f16x4 __attribute__((ext_vector_type(4)));
typedef float f32x4 __attribute__((ext_vector_type(4)));

__device__ __forceinline__ float wave_sum(float v) {
#pragma unroll
  for (int o = 32; o > 0; o >>= 1) v += __shfl_down(v, o);
  return v;
}
__device__ __forceinline__ float wave_max(float v) {
#pragma unroll
  for (int o = 32; o > 0; o >>= 1) v = fmaxf(v, __shfl_down(v, o));
  return v;
}

__device__ __forceinline__ void gld_lds16(const void* g, void* l) {
  __builtin_amdgcn_global_load_lds(
      (const __attribute__((address_space(1))) unsigned int*)g,
      (__attribute__((address_space(3))) unsigned int*)l, 16, 0, 0);
}

// ---------------------------------------------------------------------------
// fp16 MFMA GEMM: C[M,N] = epi( A[M,K] @ BT[N,K]^T + bias (+Cf) )
// 128 x BN tile, BK=64, 256 threads (4 waves, 2x2), per-wave 64 x BN/2.
// EPI: 0 none, 1 relu, 2 sigmoid, 3 tanh.  ACC adds Cf.  WOUT: 0 f32,
// 1 f16, 2 both.  M%128==0, N%BN==0, K%64==0 (true for all uses).
// ---------------------------------------------------------------------------
template <int EPI, bool ACC, int BN, int WOUT>
__global__ __launch_bounds__(256) void hgemm(
    const f16* __restrict__ A, const f16* __restrict__ BT,
    const float* __restrict__ bias, float* __restrict__ Cf,
    f16* __restrict__ Ch, int M, int N, int K,
    long sA, long sB, long sCf, long sCh) {
  constexpr int WN = BN / 2;   // wave col extent
  constexpr int FN = WN / 16;  // frags in n
  constexpr int BI = BN / 32;  // B-stage instrs per wave
  __shared__ alignas(16) f16 As[128 * 64];
  __shared__ alignas(16) f16 Bs[BN * 64];
  const int tid = threadIdx.x;
  const int lane = tid & 63, wid = tid >> 6;
  const int wm = wid >> 1, wn = wid & 1;
  const int row0 = blockIdx.y * 128, col0 = blockIdx.x * BN;
  A += blockIdx.z * sA;
  BT += blockIdx.z * sB;
  const int l8 = lane >> 3;
  const int l7 = (lane & 7) * 8;

  f32x4 acc[4][FN];
#pragma unroll
  for (int m = 0; m < 4; ++m)
#pragma unroll
    for (int n = 0; n < FN; ++n) acc[m][n] = (f32x4){0.f, 0.f, 0.f, 0.f};

  for (int k0 = 0; k0 < K; k0 += 64) {
#pragma unroll
    for (int i = 0; i < 4; ++i) {
      int r = wid * 32 + i * 8;
      gld_lds16(A + (size_t)(row0 + r + l8) * K + k0 + l7, &As[r * 64]);
    }
#pragma unroll
    for (int i = 0; i < BI; ++i) {
      int r = wid * (BN / 4) + i * 8;
      gld_lds16(BT + (size_t)(col0 + r + l8) * K + k0 + l7, &Bs[r * 64]);
    }
    __syncthreads();
#pragma unroll
    for (int ks = 0; ks < 2; ++ks) {
      f16x8 af[4], bf[FN];
#pragma unroll
      for (int m = 0; m < 4; ++m)
        af[m] = *(const f16x8*)&As[(wm * 64 + m * 16 + (lane & 15)) * 64 +
                                   ks * 32 + (lane >> 4) * 8];
#pragma unroll
      for (int n = 0; n < FN; ++n)
        bf[n] = *(const f16x8*)&Bs[(wn * WN + n * 16 + (lane & 15)) * 64 +
                                   ks * 32 + (lane >> 4) * 8];
#pragma unroll
      for (int m = 0; m < 4; ++m)
#pragma unroll
        for (int n = 0; n < FN; ++n)
          acc[m][n] =
              __builtin_amdgcn_mfma_f32_16x16x32_f16(af[m], bf[n], acc[m][n],
                                                     0, 0, 0);
    }
    __syncthreads();
  }

  const int cl = lane & 15, rh4 = (lane >> 4) * 4;
  float* Cfb = Cf + blockIdx.z * sCf;
  f16* Chb = Ch + blockIdx.z * sCh;
#pragma unroll
  for (int m = 0; m < 4; ++m) {
#pragma unroll
    for (int n = 0; n < FN; ++n) {
      int cc = col0 + wn * WN + n * 16 + cl;
      float bv = bias ? bias[cc] : 0.f;
#pragma unroll
      for (int q = 0; q < 4; ++q) {
        long r = row0 + wm * 64 + m * 16 + rh4 + q;
        float v = acc[m][n][q] + bv;
        if (ACC) v += Cfb[r * N + cc];
        if (EPI == 1) v = fmaxf(v, 0.f);
        if (EPI == 2) v = 1.f / (1.f + __expf(-v));
        if (EPI == 3) v = tanhf(v);
        if (WOUT == 0 || WOUT == 2) Cfb[r * N + cc] = v;
        if (WOUT == 1 || WOUT == 2) Chb[r * N + cc] = (f16)v;
      }
    }
  }
}

// --- fused transpose+convert of the 11 weight matrices ----------------------
struct MT {
  const float* src[11];
  f16* dst[11];
  int K[11], N[11], ts[12];
};
__global__ __launch_bounds__(256) void multi_transp(MT mt) {
  __shared__ float tile[32][33];
  int b = blockIdx.x, w = 0;
  while (b >= mt.ts[w + 1]) ++w;
  int lt = b - mt.ts[w];
  int K = mt.K[w], N = mt.N[w];
  int tk = lt % (K >> 5), tn = lt / (K >> 5);
  int k0 = tk * 32, n0 = tn * 32;
  int tx = threadIdx.x & 31, ty = threadIdx.x >> 5;
  const float* src = mt.src[w];
#pragma unroll
  for (int i = 0; i < 32; i += 8)
    tile[ty + i][tx] = src[(size_t)(k0 + ty + i) * N + n0 + tx];
  __syncthreads();
  f16* dst = mt.dst[w];
#pragma unroll
  for (int i = 0; i < 32; i += 8)
    dst[(size_t)(n0 + ty + i) * K + k0 + tx] = (f16)tile[tx][ty + i];
}

// --- generic batched tiled transpose -> fp16 --------------------------------
template <typename TIN>
__global__ __launch_bounds__(256) void transp_to_h(
    const TIN* __restrict__ in, f16* __restrict__ out, int R, int C, long sIn,
    long sOut) {
  in += blockIdx.z * sIn;
  out += blockIdx.z * sOut;
  __shared__ float tile[32][33];
  int c0 = blockIdx.x * 32, r0 = blockIdx.y * 32;
  int tx = threadIdx.x & 31, ty = threadIdx.x >> 5;
#pragma unroll
  for (int i = 0; i < 32; i += 8)
    tile[ty + i][tx] = (float)in[(size_t)(r0 + ty + i) * C + c0 + tx];
  __syncthreads();
#pragma unroll
  for (int i = 0; i < 32; i += 8)
    out[(size_t)(c0 + ty + i) * R + r0 + tx] = (f16)tile[tx][ty + i];
}

// --- f32 -> fp16 convert (n % 1024 == 0) ------------------------------------
__global__ __launch_bounds__(256) void cvt_h(const float* __restrict__ in,
                                             f16* __restrict__ out) {
  long i = ((long)blockIdx.x * 256 + threadIdx.x) * 4;
  float4 v = *(const float4*)(in + i);
  f16x4 o = {(f16)v.x, (f16)v.y, (f16)v.z, (f16)v.w};
  *(f16x4*)(out + i) = o;
}

// --- row L2-norm over 256 fp16 -> fp16 --------------------------------------
__global__ __launch_bounds__(256) void row_l2norm_h(const f16* __restrict__ in,
                                                    f16* __restrict__ out) {
  const int tid = threadIdx.x;
  long base = (long)blockIdx.x * 256;
  float v = (float)in[base + tid];
  __shared__ float red[4];
  float w = wave_sum(v * v);
  if ((tid & 63) == 0) red[tid >> 6] = w;
  __syncthreads();
  float tot = red[0] + red[1] + red[2] + red[3];
  out[base + tid] = (f16)(v / fmaxf(sqrtf(tot), 1e-12f));
}

// --- row softmax + mix with align -> fp16 -----------------------------------
__global__ __launch_bounds__(256) void softmax_mix(
    const float* __restrict__ S, const float* __restrict__ Al,
    const float* __restrict__ lam_ptr, f16* __restrict__ Mh) {
  const int tid = threadIdx.x;
  const float4* s4 = (const float4*)(S + (long)blockIdx.x * 2048);
  float4 a = s4[tid], b = s4[tid + 256];
  float m = fmaxf(fmaxf(fmaxf(a.x, a.y), fmaxf(a.z, a.w)),
                  fmaxf(fmaxf(b.x, b.y), fmaxf(b.z, b.w)));
  __shared__ float red[4];
  float w = wave_max(m);
  if ((tid & 63) == 0) red[tid >> 6] = w;
  __syncthreads();
  m = fmaxf(fmaxf(red[0], red[1]), fmaxf(red[2], red[3]));
  __syncthreads();
  a.x = __expf(a.x - m); a.y = __expf(a.y - m);
  a.z = __expf(a.z - m); a.w = __expf(a.w - m);
  b.x = __expf(b.x - m); b.y = __expf(b.y - m);
  b.z = __expf(b.z - m); b.w = __expf(b.w - m);
  float s = a.x + a.y + a.z + a.w + b.x + b.y + b.z + b.w;
  w = wave_sum(s);
  if ((tid & 63) == 0) red[tid >> 6] = w;
  __syncthreads();
  float inv = 1.f / (red[0] + red[1] + red[2] + red[3]);
  float lam = lam_ptr[0], oml = 1.f - lam;
  const float4* al4 = (const float4*)(Al + (long)blockIdx.x * 2048);
  float4 x = al4[tid], y = al4[tid + 256];
  f16x4 o0 = {(f16)(lam * x.x + oml * a.x * inv),
              (f16)(lam * x.y + oml * a.y * inv),
              (f16)(lam * x.z + oml * a.z * inv),
              (f16)(lam * x.w + oml * a.w * inv)};
  f16x4 o1 = {(f16)(lam * y.x + oml * b.x * inv),
              (f16)(lam * y.y + oml * b.y * inv),
              (f16)(lam * y.z + oml * b.z * inv),
              (f16)(lam * y.w + oml * b.w * inv)};
  f16x4* out4 = (f16x4*)(Mh + (long)blockIdx.x * 2048);
  out4[tid] = o0;
  out4[tid + 256] = o1;
}

// --- rh = fp16(r * h) --------------------------------------------------------
__global__ __launch_bounds__(256) void rh_mul_h(const float* __restrict__ gates,
                                                const float* __restrict__ h,
                                                f16* __restrict__ rh) {
  long i4 = ((long)blockIdx.x * 256 + threadIdx.x) * 4;
  int n = i4 >> 8, k = i4 & 255;
  float4 r4 = *(const float4*)(gates + (long)n * 512 + k);
  float4 h4 = *(const float4*)(h + i4);
  f16x4 o = {(f16)(r4.x * h4.x), (f16)(r4.y * h4.y), (f16)(r4.z * h4.z),
             (f16)(r4.w * h4.w)};
  *(f16x4*)(rh + i4) = o;
}

// --- rnnT16[k][n] = fp16((1-u)h + u c), tiled transpose ----------------------
__global__ __launch_bounds__(256) void rnn_mix_t(
    const float* __restrict__ gates, const float* __restrict__ h,
    const float* __restrict__ c, f16* __restrict__ rT) {
  __shared__ float tile[32][33];
  int n0 = blockIdx.x * 32, k0 = blockIdx.y * 32;
  int tx = threadIdx.x & 31, ty = threadIdx.x >> 5;
#pragma unroll
  for (int i = 0; i < 32; i += 8) {
    int n = n0 + ty + i, k = k0 + tx;
    float u = gates[(long)n * 512 + 256 + k];
    tile[ty + i][tx] = (1.f - u) * h[(long)n * 256 + k] + u * c[(long)n * 256 + k];
  }
  __syncthreads();
#pragma unroll
  for (int i = 0; i < 32; i += 8)
    rT[(size_t)(k0 + ty + i) * 2048 + n0 + tx] = (f16)tile[tx][ty + i];
}

// --- ecat16 = [fp16(h) | fem16[4]] ------------------------------------------
__global__ __launch_bounds__(256) void concat_ecat_h(
    const float* __restrict__ h, const f16* __restrict__ fem4,
    f16* __restrict__ ecat) {
  long i4 = ((long)blockIdx.x * 256 + threadIdx.x) * 4;
  int n = i4 >> 9, f = i4 & 511;
  f16x4 o;
  if (f < 256) {
    float4 v = *(const float4*)(h + (long)n * 256 + f);
    o = (f16x4){(f16)v.x, (f16)v.y, (f16)v.z, (f16)v.w};
  } else {
    o = *(const f16x4*)(fem4 + (long)n * 256 + f - 256);
  }
  *(f16x4*)(ecat + i4) = o;
}

// --- column L2 norms of emb0 [N,64] -----------------------------------------
__global__ __launch_bounds__(256) void col_l2norm64(
    const float* __restrict__ x, float* __restrict__ cn) {
  int c = blockIdx.x;
  float ss = 0.f;
  for (int r = threadIdx.x; r < NN; r += 256) {
    float v = x[(long)r * 64 + c];
    ss += v * v;
  }
  __shared__ float red[4];
  float w = wave_sum(ss);
  if ((threadIdx.x & 63) == 0) red[threadIdx.x >> 6] = w;
  __syncthreads();
  if (threadIdx.x == 0)
    cn[c] = fmaxf(sqrtf(red[0] + red[1] + red[2] + red[3]), 1e-12f);
}

// --- emb16 = emb0/cn ; sq[i] = row sumsq -------------------------------------
__global__ void norm_sq64h(const float* __restrict__ x,
                           const float* __restrict__ cn,
                           f16* __restrict__ emb16, float* __restrict__ sq) {
  int i = blockIdx.x, j = threadIdx.x;  // 64 threads
  float e = x[(long)i * 64 + j] / cn[j];
  emb16[(long)i * 64 + j] = (f16)e;
  float s = wave_sum(e * e);
  if (j == 0) sq[i] = s;
}

// --- out = 1 + tanh(-(sq_i + sq_j - 2 P) * Q) --------------------------------
__global__ __launch_bounds__(256) void final_decode(
    const float* __restrict__ P, const float* __restrict__ Q,
    const float* __restrict__ sq, float* __restrict__ out) {
  long idx = (long)blockIdx.x * 256 + threadIdx.x;
  int i = idx >> 11, j = idx & 2047;
  float dist = -(sq[i] + sq[j] - 2.f * P[idx]);
  out[idx] = 1.f + tanhf(dist * Q[idx]);
}

// ---------------------------------------------------------------------------
extern "C" void kernel_launch(void* const* d_in, const int* in_sizes, int n_in,
                              void* d_out, int out_size, void* d_ws,
                              size_t ws_size, hipStream_t stream) {
  (void)in_sizes; (void)n_in; (void)out_size; (void)ws_size;
  const float* sup    = (const float*)d_in[0];
  const float* feat   = (const float*)d_in[1];
  const float* noise  = (const float*)d_in[2];
  const float* align  = (const float*)d_in[3];
  const float* lambd  = (const float*)d_in[4];
  const float* W_fem  = (const float*)d_in[5];
  const float* b_fem  = (const float*)d_in[6];
  const float* W_gnn  = (const float*)d_in[7];
  const float* b_gnn  = (const float*)d_in[8];
  const float* Wg_x   = (const float*)d_in[9];
  const float* Wg_h   = (const float*)d_in[10];
  const float* bg     = (const float*)d_in[11];
  const float* Wc_x   = (const float*)d_in[12];
  const float* Wc_h   = (const float*)d_in[13];
  const float* bc     = (const float*)d_in[14];
  const float* W_att  = (const float*)d_in[15];
  const float* b_att  = (const float*)d_in[16];
  const float* W_emb1 = (const float*)d_in[17];
  const float* b_emb1 = (const float*)d_in[18];
  const float* W_emb2 = (const float*)d_in[19];
  const float* b_emb2 = (const float*)d_in[20];
  const float* W_scal1= (const float*)d_in[21];
  const float* b_scal1= (const float*)d_in[22];
  const float* W_scal2= (const float*)d_in[23];
  const float* b_scal2= (const float*)d_in[24];

  char* wsb = (char*)d_ws;
  size_t po = 0;
  auto P = [&](size_t bytes) {
    size_t r = po;
    po += (bytes + 255) & ~(size_t)255;
    return r;
  };
  size_t off_fem16 = P(5L * NN * HF * 2);
  size_t off_fm16  = P(5L * NN * HH * 2);
  size_t off_g16   = P(4L * NN * HH * 2);
  size_t off_WT    = P(884736L * 2);
  size_t off_hA    = P((long)NN * HH * 4);
  size_t off_hB    = P((long)NN * HH * 4);
  size_t off_h16A  = P((long)NN * HH * 2);
  size_t off_h16B  = P((long)NN * HH * 2);
  size_t off_ecat  = P((long)NN * EIN * 2);
  size_t off_e1    = P((long)NN * E1D * 2);
  size_t off_emb0  = P((long)NN * E2D * 4);
  size_t off_emb16 = P((long)NN * E2D * 2);
  size_t off_s1    = P((long)NN * E1D * 2);
  size_t off_sc16  = P((long)NN * E2D * 2);
  size_t off_cn    = P(64 * 4);
  size_t off_sq    = P(NN * 4);
  // Union A: sup16 (33.5 MB) overlaid with all scan-phase buffers
  size_t uA = po;
  size_t off_sup16 = uA;
  size_t off_S     = uA;                    // 16777216 B
  size_t off_M16   = uA + 16777216;         //  8388608 B
  size_t off_gates = uA + 25165824;         //  4194304 B
  size_t off_cbuf  = uA + 29360128;         //  2097152 B
  size_t off_rh16  = uA + 31457280;         //  1048576 B
  size_t off_rnnT  = uA + 32505856;         //  1048576 B
  // Union B: staging buffers overlaid with Qbuf
  size_t uB = uA + 33554432;
  size_t off_feat16 = uB;                   //  2621440 B
  size_t off_edmT   = uB + 2621440;         //  6291456 B
  size_t off_agg16  = uB + 2621440 + 6291456;         // 6291456 B
  size_t off_gbuf16 = uB + 2621440 + 6291456 + 6291456; // 4194304 B
  size_t off_Q      = uB;                   // 16777216 B (all dead by then)

  f16* fem16  = (f16*)(wsb + off_fem16);
  f16* fm16   = (f16*)(wsb + off_fm16);
  f16* g16    = (f16*)(wsb + off_g16);
  f16* WT     = (f16*)(wsb + off_WT);
  float* hA   = (float*)(wsb + off_hA);
  float* hB   = (float*)(wsb + off_hB);
  f16* h16A   = (f16*)(wsb + off_h16A);
  f16* h16B   = (f16*)(wsb + off_h16B);
  f16* ecat16 = (f16*)(wsb + off_ecat);
  f16* e1_16  = (f16*)(wsb + off_e1);
  float* emb0 = (float*)(wsb + off_emb0);
  f16* emb16  = (f16*)(wsb + off_emb16);
  f16* s1_16  = (f16*)(wsb + off_s1);
  f16* scal16 = (f16*)(wsb + off_sc16);
  float* cn   = (float*)(wsb + off_cn);
  float* sq   = (float*)(wsb + off_sq);
  f16* sup16  = (f16*)(wsb + off_sup16);
  float* Sbuf = (float*)(wsb + off_S);
  f16* M16    = (f16*)(wsb + off_M16);
  float* gates= (float*)(wsb + off_gates);
  float* cbuf = (float*)(wsb + off_cbuf);
  f16* rh16   = (f16*)(wsb + off_rh16);
  f16* rnnT16 = (f16*)(wsb + off_rnnT);
  f16* feat16 = (f16*)(wsb + off_feat16);
  f16* edmT   = (f16*)(wsb + off_edmT);
  f16* agg16  = (f16*)(wsb + off_agg16);
  f16* gbuf16 = (f16*)(wsb + off_gbuf16);
  float* Qbuf = (float*)(wsb + off_Q);

  // --- weight transpose table -----------------------------------------------
  const int wK[11] = {128, 384, 256, 256, 256, 256, 256, 512, 256, 512, 256};
  const int wNd[11] = {256, 256, 512, 512, 256, 256, 256, 256, 64, 256, 64};
  const float* wsrc[11] = {W_fem, W_gnn, Wg_x, Wg_h, Wc_x, Wc_h,
                           W_att, W_emb1, W_emb2, W_scal1, W_scal2};
  MT mt;
  size_t eoff = 0;
  int tcum = 0;
  f16* WTp[11];
  for (int i = 0; i < 11; ++i) {
    mt.src[i] = wsrc[i];
    mt.dst[i] = WT + eoff;
    WTp[i] = WT + eoff;
    mt.K[i] = wK[i];
    mt.N[i] = wNd[i];
    mt.ts[i] = tcum;
    eoff += (size_t)wK[i] * wNd[i];
    tcum += (wK[i] >> 5) * (wNd[i] >> 5);
  }
  mt.ts[11] = tcum;  // 864
  f16* W_femT = WTp[0], *W_gnnT = WTp[1], *WgxT = WTp[2], *WghT = WTp[3],
     *WcxT = WTp[4], *WchT = WTp[5], *W_attT = WTp[6], *Wemb1T = WTp[7],
     *Wemb2T = WTp[8], *Wscal1T = WTp[9], *Wscal2T = WTp[10];

  const float* NOF = nullptr;
  float* NF = nullptr;
  f16* NH = nullptr;

  multi_transp<<<tcum, 256, 0, stream>>>(mt);
  cvt_h<<<(5L * NN * F_IN) / 1024, 256, 0, stream>>>(feat, feat16);
  cvt_h<<<(4L * NN * NN) / 1024, 256, 0, stream>>>(sup, sup16);

  // FEM: fem16 = relu(feat @ W_fem + b)   [10240,256]
  hgemm<1, false, 64, 1><<<dim3(4, 80, 1), 256, 0, stream>>>(
      feat16, W_femT, b_fem, NF, fem16, 5 * NN, HF, F_IN, 0, 0, 0, 0);

  // edmT[t] = [fem16[t] | noise[t]]^T  [384,2048]
  transp_to_h<f16><<<dim3(8, 64, 4), 256, 0, stream>>>(
      fem16, edmT, NN, HF, (long)NN * HF, (long)G_IN * NN);
  transp_to_h<float><<<dim3(4, 64, 4), 256, 0, stream>>>(
      noise, edmT + (long)HF * NN, NN, DZ, (long)NN * DZ, (long)G_IN * NN);

  // agg16[t] = sup16[t] @ edm[t]   [2048,384] fp16
  hgemm<0, false, 64, 1><<<dim3(6, 16, 4), 256, 0, stream>>>(
      sup16, edmT, NOF, NF, agg16, NN, G_IN, NN,
      (long)NN * NN, (long)G_IN * NN, 0, (long)NN * G_IN);

  // gbuf16 = relu(agg @ W_gnn + b) ; g16 = row-l2norm
  hgemm<1, false, 64, 1><<<dim3(4, 16, 4), 256, 0, stream>>>(
      agg16, W_gnnT, b_gnn, NF, gbuf16, NN, HH, G_IN,
      (long)NN * G_IN, 0, 0, (long)NN * HH);
  row_l2norm_h<<<4 * NN, 256, 0, stream>>>(gbuf16, g16);

  // fm16 = fem @ W_att + b   [10240,256]
  hgemm<0, false, 64, 1><<<dim3(4, 80, 1), 256, 0, stream>>>(
      fem16, W_attT, b_att, NF, fm16, 5 * NN, HH, HF, 0, 0, 0, 0);

  hipMemsetAsync(hA, 0, (long)NN * HH * 4, stream);
  hipMemsetAsync(h16A, 0, (long)NN * HH * 2, stream);

  float* hcur = hA; float* hnext = hB;
  f16* h16cur = h16A; f16* h16next = h16B;
  for (int t = 0; t < T_WIN; ++t) {
    const f16* gt = g16 + (long)t * NN * HH;
    // gates = sigmoid(gt@Wgx + h@Wgh + bg)
    hgemm<0, false, 64, 0><<<dim3(8, 16, 1), 256, 0, stream>>>(
        gt, WgxT, NOF, gates, NH, NN, 512, HH, 0, 0, 0, 0);
    hgemm<2, true, 64, 0><<<dim3(8, 16, 1), 256, 0, stream>>>(
        h16cur, WghT, bg, gates, NH, NN, 512, HH, 0, 0, 0, 0);
    rh_mul_h<<<(NN * HH) / 1024, 256, 0, stream>>>(gates, hcur, rh16);
    // c = tanh(gt@Wcx + rh@Wch + bc)
    hgemm<0, false, 64, 0><<<dim3(4, 16, 1), 256, 0, stream>>>(
        gt, WcxT, NOF, cbuf, NH, NN, HH, HH, 0, 0, 0, 0);
    hgemm<3, true, 64, 0><<<dim3(4, 16, 1), 256, 0, stream>>>(
        rh16, WchT, bc, cbuf, NH, NN, HH, HH, 0, 0, 0, 0);
    rnn_mix_t<<<dim3(64, 8, 1), 256, 0, stream>>>(gates, hcur, cbuf, rnnT16);
    // S = fm[t+1] @ fm[t]^T ; softmax+mix -> M16
    hgemm<0, false, 128, 0><<<dim3(16, 16, 1), 256, 0, stream>>>(
        fm16 + (long)(t + 1) * NN * HH, fm16 + (long)t * NN * HH, NOF, Sbuf,
        NH, NN, NN, HH, 0, 0, 0, 0);
    softmax_mix<<<NN, 256, 0, stream>>>(Sbuf, align + (long)t * NN * NN,
                                        lambd, M16);
    // h_new = M16 @ rnn   (writes f32 + fp16)
    hgemm<0, false, 64, 2><<<dim3(4, 16, 1), 256, 0, stream>>>(
        M16, rnnT16, NOF, hnext, h16next, NN, HH, NN, 0, 0, 0, 0);
    float* tf = hcur; hcur = hnext; hnext = tf;
    f16* th = h16cur; h16cur = h16next; h16next = th;
  }

  // --- EAM -------------------------------------------------------------------
  concat_ecat_h<<<(NN * EIN) / 1024, 256, 0, stream>>>(
      hcur, fem16 + 4L * NN * HF, ecat16);
  hgemm<3, false, 64, 1><<<dim3(4, 16, 1), 256, 0, stream>>>(
      ecat16, Wemb1T, b_emb1, NF, e1_16, NN, E1D, EIN, 0, 0, 0, 0);
  hgemm<3, false, 64, 0><<<dim3(1, 16, 1), 256, 0, stream>>>(
      e1_16, Wemb2T, b_emb2, emb0, NH, NN, E2D, E1D, 0, 0, 0, 0);
  col_l2norm64<<<64, 256, 0, stream>>>(emb0, cn);
  norm_sq64h<<<NN, 64, 0, stream>>>(emb0, cn, emb16, sq);
  hgemm<2, false, 64, 1><<<dim3(4, 16, 1), 256, 0, stream>>>(
      ecat16, Wscal1T, b_scal1, NF, s1_16, NN, E1D, EIN, 0, 0, 0, 0);
  hgemm<2, false, 64, 1><<<dim3(1, 16, 1), 256, 0, stream>>>(
      s1_16, Wscal2T, b_scal2, NF, scal16, NN, E2D, E1D, 0, 0, 0, 0);

  // P = emb@emb^T -> Sbuf ; Q = scal@scal^T -> Qbuf
  hgemm<0, false, 128, 0><<<dim3(16, 16, 1), 256, 0, stream>>>(
      emb16, emb16, NOF, Sbuf, NH, NN, NN, E2D, 0, 0, 0, 0);
  hgemm<0, false, 128, 0><<<dim3(16, 16, 1), 256, 0, stream>>>(
      scal16, scal16, NOF, Qbuf, NH, NN, NN, E2D, 0, 0, 0, 0);

  final_decode<<<(NN * NN) / 256, 256, 0, stream>>>(Sbuf, Qbuf, sq,
                                                    (float*)d_out);
}

// Round 3
// 487.911 us; speedup vs baseline: 3.3032x; 1.2017x over previous
//
#include <hip/hip_runtime.h>
#include <math.h>

// ---------------------------------------------------------------------------
// GenNet_tanh forward, round 3: fp16 MFMA everywhere + LDS XOR swizzle,
// fused sup->agg->gnn->l2norm megakernel, fused GRU gate/candidate GEMMs,
// fused P/Q/decode tail.  37 dispatches.
// ---------------------------------------------------------------------------

#define T_WIN 4
#define NN 2048
#define F_IN 128
#define HF 256
#define HH 256
#define DZ 128
#define G_IN 384
#define EIN 512
#define E1D 256
#define E2D 64

typedef _Float16 f16;
typedef _Float16 f16x8 __attribute__((ext_vector_type(8)));
typedef _Float16 f16x4 __attribute__((ext_vector_type(4)));
typedef float f32x4 __attribute__((ext_vector_type(4)));

__device__ __forceinline__ float wave_sum(float v) {
#pragma unroll
  for (int o = 32; o > 0; o >>= 1) v += __shfl_down(v, o);
  return v;
}
__device__ __forceinline__ float wave_max(float v) {
#pragma unroll
  for (int o = 32; o > 0; o >>= 1) v = fmaxf(v, __shfl_down(v, o));
  return v;
}

__device__ __forceinline__ void gld_lds16(const void* g, void* l) {
  __builtin_amdgcn_global_load_lds(
      (const __attribute__((address_space(1))) unsigned int*)g,
      (__attribute__((address_space(3))) unsigned int*)l, 16, 0, 0);
}

// ---------------------------------------------------------------------------
// fp16 MFMA GEMM, 128 x BN tile, BK=64, 256 threads (4 waves 2x2).
// A: [M,K] row-major, dual-source: k<kspl from A (stride kspl), else A2
// (stride K-kspl).  BT: [N,K] row-major.  LDS XOR-swizzled (16B granule).
// EPI: 0 none, 1 relu, 2 sigmoid, 3 tanh, 4 GRU-gates (rh16/ubuf epilogue).
// WOUT: 0 f32, 1 f16, 2 both.
// ---------------------------------------------------------------------------
template <int EPI, int BN, int WOUT>
__global__ __launch_bounds__(256) void hgemm(
    const f16* __restrict__ A, const f16* __restrict__ A2, int kspl,
    const f16* __restrict__ BT, const float* __restrict__ bias,
    float* __restrict__ Cf, f16* __restrict__ Ch,
    const float* __restrict__ X1f, const float* __restrict__ Xu_in,
    f16* __restrict__ Xrh, float* __restrict__ Xu_out, int M, int N, int K) {
  constexpr int WN = BN / 2;
  constexpr int FN = WN / 16;
  constexpr int BI = BN / 32;
  __shared__ alignas(16) f16 As[128 * 64];
  __shared__ alignas(16) f16 Bs[BN * 64];
  const int tid = threadIdx.x;
  const int lane = tid & 63, wid = tid >> 6;
  const int wm = wid >> 1, wn = wid & 1;
  const int row0 = blockIdx.y * 128, col0 = blockIdx.x * BN;
  const int l8 = lane >> 3;
  const int lx = ((lane & 7) ^ l8) * 8;  // pre-swizzled source chunk
  const int sw = (lane & 7) * 8;         // frag-read XOR
  const int sA2 = K - kspl;

  f32x4 acc[4][FN];
#pragma unroll
  for (int m = 0; m < 4; ++m)
#pragma unroll
    for (int n = 0; n < FN; ++n) acc[m][n] = (f32x4){0.f, 0.f, 0.f, 0.f};

  for (int k0 = 0; k0 < K; k0 += 64) {
#pragma unroll
    for (int i = 0; i < 4; ++i) {
      int r = wid * 32 + i * 8;
      const f16* src =
          (k0 < kspl) ? A + (size_t)(row0 + r + l8) * kspl + k0 + lx
                      : A2 + (size_t)(row0 + r + l8) * sA2 + (k0 - kspl) + lx;
      gld_lds16(src, &As[r * 64]);
    }
#pragma unroll
    for (int i = 0; i < BI; ++i) {
      int r = wid * (BN / 4) + i * 8;
      gld_lds16(BT + (size_t)(col0 + r + l8) * K + k0 + lx, &Bs[r * 64]);
    }
    __syncthreads();
#pragma unroll
    for (int ks = 0; ks < 2; ++ks) {
      f16x8 af[4], bf[FN];
#pragma unroll
      for (int m = 0; m < 4; ++m)
        af[m] = *(const f16x8*)&As[((wm * 64 + m * 16 + (lane & 15)) * 64 +
                                    ks * 32 + (lane >> 4) * 8) ^ sw];
#pragma unroll
      for (int n = 0; n < FN; ++n)
        bf[n] = *(const f16x8*)&Bs[((wn * WN + n * 16 + (lane & 15)) * 64 +
                                    ks * 32 + (lane >> 4) * 8) ^ sw];
#pragma unroll
      for (int m = 0; m < 4; ++m)
#pragma unroll
        for (int n = 0; n < FN; ++n)
          acc[m][n] = __builtin_amdgcn_mfma_f32_16x16x32_f16(af[m], bf[n],
                                                             acc[m][n], 0, 0, 0);
    }
    __syncthreads();
  }

  const int cl = lane & 15, rh4 = (lane >> 4) * 4;
#pragma unroll
  for (int m = 0; m < 4; ++m) {
#pragma unroll
    for (int n = 0; n < FN; ++n) {
      int cc = col0 + wn * WN + n * 16 + cl;
      float bv = bias ? bias[cc] : 0.f;
#pragma unroll
      for (int q = 0; q < 4; ++q) {
        size_t r = row0 + wm * 64 + m * 16 + rh4 + q;
        float v = acc[m][n][q] + bv;
        if (EPI == 4) {
          float sv = 1.f / (1.f + __expf(-v));
          if (cc < 256)
            Xrh[r * 256 + cc] = (f16)(sv * X1f[r * 256 + cc]);
          else
            Xu_out[r * 256 + cc - 256] = sv;
        } else {
          if (EPI == 1) v = fmaxf(v, 0.f);
          if (EPI == 2) v = 1.f / (1.f + __expf(-v));
          if (EPI == 3) v = tanhf(v);
          if (WOUT == 0 || WOUT == 2) Cf[r * N + cc] = v;
          if (WOUT == 1 || WOUT == 2) Ch[r * N + cc] = (f16)v;
        }
      }
    }
  }
}

// ---------------------------------------------------------------------------
// Candidate GEMM + GRU mix + transposed write: c = tanh([gt|rh]@Wccat + bc),
// rnn = (1-u)h + u*c, write rnnT16[k][n] (transposed via LDS).  BN=64.
// ---------------------------------------------------------------------------
__global__ __launch_bounds__(256) void cgemm_rnnT(
    const f16* __restrict__ A, const f16* __restrict__ A2,
    const f16* __restrict__ BT, const float* __restrict__ bias,
    const float* __restrict__ hf, const float* __restrict__ ubuf,
    f16* __restrict__ rnnT) {
  constexpr int K = 512, kspl = 256;
  __shared__ alignas(16) f16 As[128 * 64];
  __shared__ alignas(16) f16 Bs[64 * 64];
  __shared__ alignas(16) f16 tileT[64 * 136];
  const int tid = threadIdx.x;
  const int lane = tid & 63, wid = tid >> 6;
  const int wm = wid >> 1, wn = wid & 1;
  const int row0 = blockIdx.y * 128, col0 = blockIdx.x * 64;
  const int l8 = lane >> 3;
  const int lx = ((lane & 7) ^ l8) * 8;
  const int sw = (lane & 7) * 8;

  f32x4 acc[4][2];
#pragma unroll
  for (int m = 0; m < 4; ++m)
#pragma unroll
    for (int n = 0; n < 2; ++n) acc[m][n] = (f32x4){0.f, 0.f, 0.f, 0.f};

  for (int k0 = 0; k0 < K; k0 += 64) {
#pragma unroll
    for (int i = 0; i < 4; ++i) {
      int r = wid * 32 + i * 8;
      const f16* src =
          (k0 < kspl) ? A + (size_t)(row0 + r + l8) * 256 + k0 + lx
                      : A2 + (size_t)(row0 + r + l8) * 256 + (k0 - 256) + lx;
      gld_lds16(src, &As[r * 64]);
    }
#pragma unroll
    for (int i = 0; i < 2; ++i) {
      int r = wid * 16 + i * 8;
      gld_lds16(BT + (size_t)(col0 + r + l8) * K + k0 + lx, &Bs[r * 64]);
    }
    __syncthreads();
#pragma unroll
    for (int ks = 0; ks < 2; ++ks) {
      f16x8 af[4], bf[2];
#pragma unroll
      for (int m = 0; m < 4; ++m)
        af[m] = *(const f16x8*)&As[((wm * 64 + m * 16 + (lane & 15)) * 64 +
                                    ks * 32 + (lane >> 4) * 8) ^ sw];
#pragma unroll
      for (int n = 0; n < 2; ++n)
        bf[n] = *(const f16x8*)&Bs[((wn * 32 + n * 16 + (lane & 15)) * 64 +
                                    ks * 32 + (lane >> 4) * 8) ^ sw];
#pragma unroll
      for (int m = 0; m < 4; ++m)
#pragma unroll
        for (int n = 0; n < 2; ++n)
          acc[m][n] = __builtin_amdgcn_mfma_f32_16x16x32_f16(af[m], bf[n],
                                                             acc[m][n], 0, 0, 0);
    }
    __syncthreads();
  }

  const int cl = lane & 15, rh4 = (lane >> 4) * 4;
#pragma unroll
  for (int m = 0; m < 4; ++m) {
#pragma unroll
    for (int n = 0; n < 2; ++n) {
      int ccl = wn * 32 + n * 16 + cl;
      int cc = col0 + ccl;
      float bv = bias[cc];
#pragma unroll
      for (int q = 0; q < 4; ++q) {
        int rl = wm * 64 + m * 16 + rh4 + q;
        size_t r = row0 + rl;
        float c = tanhf(acc[m][n][q] + bv);
        float u = ubuf[r * 256 + cc];
        float h = hf[r * 256 + cc];
        tileT[ccl * 136 + rl] = (f16)((1.f - u) * h + u * c);
      }
    }
  }
  __syncthreads();
#pragma unroll
  for (int i = 0; i < 4; ++i) {
    int chunk = i * 256 + tid;  // 1024 chunks of 8
    int rr = chunk >> 4, seg = (chunk & 15) * 8;
    *(f16x8*)&rnnT[(size_t)(col0 + rr) * NN + row0 + seg] =
        *(const f16x8*)&tileT[rr * 136 + seg];
  }
}

// ---------------------------------------------------------------------------
// Fused sup-path: g16[t] = l2norm(relu( (sup[t]@edm[t]) @ Wgnn + b ))
// Block: 32 rows, all 384 mid-cols, all 256 out-cols.  256 thr, 4 waves.
// ---------------------------------------------------------------------------
__global__ __launch_bounds__(256) void sup_gnn(
    const float* __restrict__ sup, const f16* __restrict__ edmT,
    const f16* __restrict__ WgnnT, const float* __restrict__ bgnn,
    f16* __restrict__ g16) {
  __shared__ alignas(16) f16 Bs[384 * 64];
  __shared__ alignas(16) f16 As[32 * 64];
  __shared__ alignas(16) f16 aggS[32 * 392];
  __shared__ float red[4][32];
  const int tid = threadIdx.x;
  const int lane = tid & 63, wid = tid >> 6;
  const int t = blockIdx.y, m0 = blockIdx.x * 32;
  const int l8 = lane >> 3;
  const int lx = ((lane & 7) ^ l8) * 8;
  const int sw = (lane & 7) * 8;
  const int cl = lane & 15, hi = lane >> 4;

  const float* supT = sup + (size_t)t * NN * NN;
  const f16* edmTt = edmT + (size_t)t * G_IN * NN;

  f32x4 acc[2][6];
#pragma unroll
  for (int m = 0; m < 2; ++m)
#pragma unroll
    for (int n = 0; n < 6; ++n) acc[m][n] = (f32x4){0.f, 0.f, 0.f, 0.f};

  const int ar = tid >> 3;
  const int acw = ((tid & 7) ^ (ar & 7)) * 8;  // swizzled write chunk

  for (int k0 = 0; k0 < NN; k0 += 64) {
    const float* ap = supT + (size_t)(m0 + ar) * NN + k0 + ((tid & 7) * 8);
    float4 f0 = *(const float4*)ap;
    float4 f1 = *(const float4*)(ap + 4);
    // swizzled store: chunk (tid&7) of row ar lands at chunk (tid&7)^(ar&7)
    f16x8 hv = {(f16)f0.x, (f16)f0.y, (f16)f0.z, (f16)f0.w,
                (f16)f1.x, (f16)f1.y, (f16)f1.z, (f16)f1.w};
    *(f16x8*)&As[ar * 64 + acw] = hv;
#pragma unroll
    for (int i = 0; i < 12; ++i) {
      int rn = wid * 96 + i * 8;
      gld_lds16(edmTt + (size_t)(rn + l8) * NN + k0 + lx, &Bs[rn * 64]);
    }
    __syncthreads();
#pragma unroll
    for (int ks = 0; ks < 2; ++ks) {
      f16x8 af[2], bf[6];
#pragma unroll
      for (int m = 0; m < 2; ++m)
        af[m] = *(const f16x8*)&As[((m * 16 + cl) * 64 + ks * 32 + hi * 8) ^ sw];
#pragma unroll
      for (int n = 0; n < 6; ++n)
        bf[n] = *(const f16x8*)&Bs[((wid * 96 + n * 16 + cl) * 64 + ks * 32 +
                                    hi * 8) ^ sw];
#pragma unroll
      for (int m = 0; m < 2; ++m)
#pragma unroll
        for (int n = 0; n < 6; ++n)
          acc[m][n] = __builtin_amdgcn_mfma_f32_16x16x32_f16(af[m], bf[n],
                                                             acc[m][n], 0, 0, 0);
    }
    __syncthreads();
  }
  // wait, hold the sw note: As was written swizzled per-row ✓, reads XOR sw ✓
#pragma unroll
  for (int m = 0; m < 2; ++m)
#pragma unroll
    for (int n = 0; n < 6; ++n)
#pragma unroll
      for (int q = 0; q < 4; ++q)
        aggS[(m * 16 + hi * 4 + q) * 392 + wid * 96 + n * 16 + cl] =
            (f16)acc[m][n][q];
  __syncthreads();

  f32x4 acc2[2][4];
#pragma unroll
  for (int m = 0; m < 2; ++m)
#pragma unroll
    for (int n = 0; n < 4; ++n) acc2[m][n] = (f32x4){0.f, 0.f, 0.f, 0.f};

  for (int k0 = 0; k0 < G_IN; k0 += 64) {
#pragma unroll
    for (int i = 0; i < 8; ++i) {
      int rn = wid * 64 + i * 8;
      gld_lds16(WgnnT + (size_t)(rn + l8) * G_IN + k0 + lx, &Bs[rn * 64]);
    }
    __syncthreads();
#pragma unroll
    for (int ks = 0; ks < 2; ++ks) {
      f16x8 af[2], bf[4];
#pragma unroll
      for (int m = 0; m < 2; ++m)
        af[m] = *(const f16x8*)&aggS[(m * 16 + cl) * 392 + k0 + ks * 32 + hi * 8];
#pragma unroll
      for (int n = 0; n < 4; ++n)
        bf[n] = *(const f16x8*)&Bs[((wid * 64 + n * 16 + cl) * 64 + ks * 32 +
                                    hi * 8) ^ sw];
#pragma unroll
      for (int m = 0; m < 2; ++m)
#pragma unroll
        for (int n = 0; n < 4; ++n)
          acc2[m][n] = __builtin_amdgcn_mfma_f32_16x16x32_f16(af[m], bf[n],
                                                              acc2[m][n], 0, 0, 0);
    }
    __syncthreads();
  }
  // relu + bias, keep in acc2
#pragma unroll
  for (int m = 0; m < 2; ++m)
#pragma unroll
    for (int n = 0; n < 4; ++n) {
      float bv = bgnn[wid * 64 + n * 16 + cl];
#pragma unroll
      for (int q = 0; q < 4; ++q)
        acc2[m][n][q] = fmaxf(acc2[m][n][q] + bv, 0.f);
    }
  // row sumsq across 16-lane groups then across waves
#pragma unroll
  for (int m = 0; m < 2; ++m)
#pragma unroll
    for (int q = 0; q < 4; ++q) {
      float ss = 0.f;
#pragma unroll
      for (int n = 0; n < 4; ++n) ss += acc2[m][n][q] * acc2[m][n][q];
#pragma unroll
      for (int msk = 1; msk < 16; msk <<= 1) ss += __shfl_xor(ss, msk);
      if (cl == 0) red[wid][m * 16 + hi * 4 + q] = ss;
    }
  __syncthreads();
#pragma unroll
  for (int m = 0; m < 2; ++m)
#pragma unroll
    for (int q = 0; q < 4; ++q) {
      int row = m * 16 + hi * 4 + q;
      float tot = red[0][row] + red[1][row] + red[2][row] + red[3][row];
      float inv = 1.f / fmaxf(sqrtf(tot), 1e-12f);
#pragma unroll
      for (int n = 0; n < 4; ++n)
        g16[((size_t)t * NN + m0 + row) * 256 + wid * 64 + n * 16 + cl] =
            (f16)(acc2[m][n][q] * inv);
    }
}

// ---------------------------------------------------------------------------
// Fused P/Q/decode: out = 1 + tanh(-(sq_i+sq_j-2*emb@emb^T)*(scal@scal^T))
// ---------------------------------------------------------------------------
__global__ __launch_bounds__(256) void pq_decode(
    const f16* __restrict__ emb, const f16* __restrict__ scal,
    const float* __restrict__ sq, float* __restrict__ out) {
  __shared__ alignas(16) f16 EA[128 * 64], EB[128 * 64], SA[128 * 64],
      SB[128 * 64];
  const int tid = threadIdx.x;
  const int lane = tid & 63, wid = tid >> 6;
  const int wm = wid >> 1, wn = wid & 1;
  const int row0 = blockIdx.y * 128, col0 = blockIdx.x * 128;
  const int l8 = lane >> 3;
  const int lx = ((lane & 7) ^ l8) * 8;
  const int sw = (lane & 7) * 8;
#pragma unroll
  for (int i = 0; i < 2; ++i) {
    int r = wid * 16 + i * 8;
    gld_lds16(emb + (size_t)(row0 + r + l8) * 64 + lx, &EA[r * 64]);
    gld_lds16(emb + (size_t)(col0 + r + l8) * 64 + lx, &EB[r * 64]);
    gld_lds16(scal + (size_t)(row0 + r + l8) * 64 + lx, &SA[r * 64]);
    gld_lds16(scal + (size_t)(col0 + r + l8) * 64 + lx, &SB[r * 64]);
    int r2 = r + 64;
    gld_lds16(emb + (size_t)(row0 + r2 + l8) * 64 + lx, &EA[r2 * 64]);
    gld_lds16(emb + (size_t)(col0 + r2 + l8) * 64 + lx, &EB[r2 * 64]);
    gld_lds16(scal + (size_t)(row0 + r2 + l8) * 64 + lx, &SA[r2 * 64]);
    gld_lds16(scal + (size_t)(col0 + r2 + l8) * 64 + lx, &SB[r2 * 64]);
  }
  __syncthreads();
  f32x4 accP[4][4], accQ[4][4];
#pragma unroll
  for (int m = 0; m < 4; ++m)
#pragma unroll
    for (int n = 0; n < 4; ++n) {
      accP[m][n] = (f32x4){0.f, 0.f, 0.f, 0.f};
      accQ[m][n] = (f32x4){0.f, 0.f, 0.f, 0.f};
    }
#pragma unroll
  for (int ks = 0; ks < 2; ++ks) {
    f16x8 af[4], bf[4];
#pragma unroll
    for (int m = 0; m < 4; ++m)
      af[m] = *(const f16x8*)&EA[((wm * 64 + m * 16 + (lane & 15)) * 64 +
                                  ks * 32 + (lane >> 4) * 8) ^ sw];
#pragma unroll
    for (int n = 0; n < 4; ++n)
      bf[n] = *(const f16x8*)&EB[((wn * 64 + n * 16 + (lane & 15)) * 64 +
                                  ks * 32 + (lane >> 4) * 8) ^ sw];
#pragma unroll
    for (int m = 0; m < 4; ++m)
#pragma unroll
      for (int n = 0; n < 4; ++n)
        accP[m][n] = __builtin_amdgcn_mfma_f32_16x16x32_f16(af[m], bf[n],
                                                            accP[m][n], 0, 0, 0);
#pragma unroll
    for (int m = 0; m < 4; ++m)
      af[m] = *(const f16x8*)&SA[((wm * 64 + m * 16 + (lane & 15)) * 64 +
                                  ks * 32 + (lane >> 4) * 8) ^ sw];
#pragma unroll
    for (int n = 0; n < 4; ++n)
      bf[n] = *(const f16x8*)&SB[((wn * 64 + n * 16 + (lane & 15)) * 64 +
                                  ks * 32 + (lane >> 4) * 8) ^ sw];
#pragma unroll
    for (int m = 0; m < 4; ++m)
#pragma unroll
      for (int n = 0; n < 4; ++n)
        accQ[m][n] = __builtin_amdgcn_mfma_f32_16x16x32_f16(af[m], bf[n],
                                                            accQ[m][n], 0, 0, 0);
  }
  const int cl = lane & 15, rh4 = (lane >> 4) * 4;
#pragma unroll
  for (int m = 0; m < 4; ++m) {
#pragma unroll
    for (int n = 0; n < 4; ++n) {
      int c = col0 + wn * 64 + n * 16 + cl;
      float sqc = sq[c];
#pragma unroll
      for (int q = 0; q < 4; ++q) {
        size_t r = row0 + wm * 64 + m * 16 + rh4 + q;
        float dist = -(sq[r] + sqc - 2.f * accP[m][n][q]);
        out[r * NN + c] = 1.f + tanhf(dist * accQ[m][n][q]);
      }
    }
  }
}

// --- fused transpose+convert of the weight matrices --------------------------
struct MT {
  const float* src[11];
  f16* dst[11];
  int K[11], N[11], st[11], co[11], ts[12];
};
__global__ __launch_bounds__(256) void multi_transp(MT mt) {
  __shared__ float tile[32][33];
  int b = blockIdx.x, w = 0;
  while (b >= mt.ts[w + 1]) ++w;
  int lt = b - mt.ts[w];
  int K = mt.K[w], N = mt.N[w];
  int tk = lt % (K >> 5), tn = lt / (K >> 5);
  int k0 = tk * 32, n0 = tn * 32;
  int tx = threadIdx.x & 31, ty = threadIdx.x >> 5;
  const float* src = mt.src[w];
#pragma unroll
  for (int i = 0; i < 32; i += 8)
    tile[ty + i][tx] = src[(size_t)(k0 + ty + i) * N + n0 + tx];
  __syncthreads();
  f16* dst = mt.dst[w];
  int st = mt.st[w], co = mt.co[w];
#pragma unroll
  for (int i = 0; i < 32; i += 8)
    dst[(size_t)(n0 + ty + i) * st + co + k0 + tx] = (f16)tile[tx][ty + i];
}

// --- generic batched tiled transpose -> fp16 ---------------------------------
template <typename TIN>
__global__ __launch_bounds__(256) void transp_to_h(
    const TIN* __restrict__ in, f16* __restrict__ out, int R, int C, long sIn,
    long sOut) {
  in += blockIdx.z * sIn;
  out += blockIdx.z * sOut;
  __shared__ float tile[32][33];
  int c0 = blockIdx.x * 32, r0 = blockIdx.y * 32;
  int tx = threadIdx.x & 31, ty = threadIdx.x >> 5;
#pragma unroll
  for (int i = 0; i < 32; i += 8)
    tile[ty + i][tx] = (float)in[(size_t)(r0 + ty + i) * C + c0 + tx];
  __syncthreads();
#pragma unroll
  for (int i = 0; i < 32; i += 8)
    out[(size_t)(c0 + ty + i) * R + r0 + tx] = (f16)tile[tx][ty + i];
}

// --- f32 -> fp16 convert -----------------------------------------------------
__global__ __launch_bounds__(256) void cvt_h(const float* __restrict__ in,
                                             f16* __restrict__ out) {
  long i = ((long)blockIdx.x * 256 + threadIdx.x) * 4;
  float4 v = *(const float4*)(in + i);
  f16x4 o = {(f16)v.x, (f16)v.y, (f16)v.z, (f16)v.w};
  *(f16x4*)(out + i) = o;
}

// --- row softmax + mix with align -> fp16 ------------------------------------
__global__ __launch_bounds__(256) void softmax_mix(
    const float* __restrict__ S, const float* __restrict__ Al,
    const float* __restrict__ lam_ptr, f16* __restrict__ Mh) {
  const int tid = threadIdx.x;
  const float4* s4 = (const float4*)(S + (long)blockIdx.x * 2048);
  float4 a = s4[tid], b = s4[tid + 256];
  float m = fmaxf(fmaxf(fmaxf(a.x, a.y), fmaxf(a.z, a.w)),
                  fmaxf(fmaxf(b.x, b.y), fmaxf(b.z, b.w)));
  __shared__ float red[4];
  float w = wave_max(m);
  if ((tid & 63) == 0) red[tid >> 6] = w;
  __syncthreads();
  m = fmaxf(fmaxf(red[0], red[1]), fmaxf(red[2], red[3]));
  __syncthreads();
  a.x = __expf(a.x - m); a.y = __expf(a.y - m);
  a.z = __expf(a.z - m); a.w = __expf(a.w - m);
  b.x = __expf(b.x - m); b.y = __expf(b.y - m);
  b.z = __expf(b.z - m); b.w = __expf(b.w - m);
  float s = a.x + a.y + a.z + a.w + b.x + b.y + b.z + b.w;
  w = wave_sum(s);
  if ((tid & 63) == 0) red[tid >> 6] = w;
  __syncthreads();
  float inv = 1.f / (red[0] + red[1] + red[2] + red[3]);
  float lam = lam_ptr[0], oml = 1.f - lam;
  const float4* al4 = (const float4*)(Al + (long)blockIdx.x * 2048);
  float4 x = al4[tid], y = al4[tid + 256];
  f16x4 o0 = {(f16)(lam * x.x + oml * a.x * inv),
              (f16)(lam * x.y + oml * a.y * inv),
              (f16)(lam * x.z + oml * a.z * inv),
              (f16)(lam * x.w + oml * a.w * inv)};
  f16x4 o1 = {(f16)(lam * y.x + oml * b.x * inv),
              (f16)(lam * y.y + oml * b.y * inv),
              (f16)(lam * y.z + oml * b.z * inv),
              (f16)(lam * y.w + oml * b.w * inv)};
  f16x4* out4 = (f16x4*)(Mh + (long)blockIdx.x * 2048);
  out4[tid] = o0;
  out4[tid + 256] = o1;
}

// --- ecat16 = [fp16(h) | fem16[4]] -------------------------------------------
__global__ __launch_bounds__(256) void concat_ecat_h(
    const float* __restrict__ h, const f16* __restrict__ fem4,
    f16* __restrict__ ecat) {
  long i4 = ((long)blockIdx.x * 256 + threadIdx.x) * 4;
  int n = i4 >> 9, f = i4 & 511;
  f16x4 o;
  if (f < 256) {
    float4 v = *(const float4*)(h + (long)n * 256 + f);
    o = (f16x4){(f16)v.x, (f16)v.y, (f16)v.z, (f16)v.w};
  } else {
    o = *(const f16x4*)(fem4 + (long)n * 256 + f - 256);
  }
  *(f16x4*)(ecat + i4) = o;
}

// --- column L2 norms of emb0 [N,64] ------------------------------------------
__global__ __launch_bounds__(256) void col_l2norm64(
    const float* __restrict__ x, float* __restrict__ cn) {
  int c = blockIdx.x;
  float ss = 0.f;
  for (int r = threadIdx.x; r < NN; r += 256) {
    float v = x[(long)r * 64 + c];
    ss += v * v;
  }
  __shared__ float red[4];
  float w = wave_sum(ss);
  if ((threadIdx.x & 63) == 0) red[threadIdx.x >> 6] = w;
  __syncthreads();
  if (threadIdx.x == 0)
    cn[c] = fmaxf(sqrtf(red[0] + red[1] + red[2] + red[3]), 1e-12f);
}

// --- emb16 = emb0/cn ; sq[i] = row sumsq -------------------------------------
__global__ void norm_sq64h(const float* __restrict__ x,
                           const float* __restrict__ cn,
                           f16* __restrict__ emb16, float* __restrict__ sq) {
  int i = blockIdx.x, j = threadIdx.x;  // 64 threads
  float e = x[(long)i * 64 + j] / cn[j];
  emb16[(long)i * 64 + j] = (f16)e;
  float s = wave_sum(e * e);
  if (j == 0) sq[i] = s;
}

// ---------------------------------------------------------------------------
extern "C" void kernel_launch(void* const* d_in, const int* in_sizes, int n_in,
                              void* d_out, int out_size, void* d_ws,
                              size_t ws_size, hipStream_t stream) {
  (void)in_sizes; (void)n_in; (void)out_size; (void)ws_size;
  const float* sup    = (const float*)d_in[0];
  const float* feat   = (const float*)d_in[1];
  const float* noise  = (const float*)d_in[2];
  const float* align  = (const float*)d_in[3];
  const float* lambd  = (const float*)d_in[4];
  const float* W_fem  = (const float*)d_in[5];
  const float* b_fem  = (const float*)d_in[6];
  const float* W_gnn  = (const float*)d_in[7];
  const float* b_gnn  = (const float*)d_in[8];
  const float* Wg_x   = (const float*)d_in[9];
  const float* Wg_h   = (const float*)d_in[10];
  const float* bg     = (const float*)d_in[11];
  const float* Wc_x   = (const float*)d_in[12];
  const float* Wc_h   = (const float*)d_in[13];
  const float* bc     = (const float*)d_in[14];
  const float* W_att  = (const float*)d_in[15];
  const float* b_att  = (const float*)d_in[16];
  const float* W_emb1 = (const float*)d_in[17];
  const float* b_emb1 = (const float*)d_in[18];
  const float* W_emb2 = (const float*)d_in[19];
  const float* b_emb2 = (const float*)d_in[20];
  const float* W_scal1= (const float*)d_in[21];
  const float* b_scal1= (const float*)d_in[22];
  const float* W_scal2= (const float*)d_in[23];
  const float* b_scal2= (const float*)d_in[24];

  char* wsb = (char*)d_ws;
  size_t po = 0;
  auto P = [&](size_t bytes) {
    size_t r = po;
    po += (bytes + 255) & ~(size_t)255;
    return r;
  };
  f16* fem16  = (f16*)(wsb + P(5L * NN * HF * 2));
  f16* fm16   = (f16*)(wsb + P(5L * NN * HH * 2));
  f16* g16    = (f16*)(wsb + P(4L * NN * HH * 2));
  f16* WT     = (f16*)(wsb + P(884736L * 2));
  f16* edmT   = (f16*)(wsb + P(4L * G_IN * NN * 2));
  f16* feat16 = (f16*)(wsb + P(5L * NN * F_IN * 2));
  float* hA   = (float*)(wsb + P((long)NN * HH * 4));
  float* hB   = (float*)(wsb + P((long)NN * HH * 4));
  f16* h16A   = (f16*)(wsb + P((long)NN * HH * 2));
  f16* h16B   = (f16*)(wsb + P((long)NN * HH * 2));
  float* ubuf = (float*)(wsb + P((long)NN * HH * 4));
  f16* rh16   = (f16*)(wsb + P((long)NN * HH * 2));
  f16* rnnT16 = (f16*)(wsb + P((long)NN * HH * 2));
  float* Sbuf = (float*)(wsb + P((long)NN * NN * 4));
  f16* M16    = (f16*)(wsb + P((long)NN * NN * 2));
  f16* ecat16 = (f16*)(wsb + P((long)NN * EIN * 2));
  f16* e1_16  = (f16*)(wsb + P((long)NN * E1D * 2));
  float* emb0 = (float*)(wsb + P((long)NN * E2D * 4));
  f16* emb16  = (f16*)(wsb + P((long)NN * E2D * 2));
  f16* s1_16  = (f16*)(wsb + P((long)NN * E1D * 2));
  f16* scal16 = (f16*)(wsb + P((long)NN * E2D * 2));
  float* cn   = (float*)(wsb + P(64 * 4));
  float* sq   = (float*)(wsb + P(NN * 4));

  // --- weight transpose/cat table -------------------------------------------
  // dst elem counts: fem 32768, gnn 98304, gcat 262144, ccat 131072,
  // att 65536, emb1 131072, emb2 16384, scal1 131072, scal2 16384
  f16* W_femT  = WT;
  f16* W_gnnT  = W_femT + 32768;
  f16* WgcatT  = W_gnnT + 98304;
  f16* WccatT  = WgcatT + 262144;
  f16* W_attT  = WccatT + 131072;
  f16* Wemb1T  = W_attT + 65536;
  f16* Wemb2T  = Wemb1T + 131072;
  f16* Wscal1T = Wemb2T + 16384;
  f16* Wscal2T = Wscal1T + 131072;

  MT mt;
  const float* wsrc[11] = {W_fem, W_gnn, Wg_x, Wg_h, Wc_x, Wc_h,
                           W_att, W_emb1, W_emb2, W_scal1, W_scal2};
  f16* wdst[11] = {W_femT, W_gnnT, WgcatT, WgcatT, WccatT, WccatT,
                   W_attT, Wemb1T, Wemb2T, Wscal1T, Wscal2T};
  const int wK[11] = {128, 384, 256, 256, 256, 256, 256, 512, 256, 512, 256};
  const int wNd[11] = {256, 256, 512, 512, 256, 256, 256, 256, 64, 256, 64};
  const int wSt[11] = {128, 384, 512, 512, 512, 512, 256, 512, 256, 512, 256};
  const int wCo[11] = {0, 0, 0, 256, 0, 256, 0, 0, 0, 0, 0};
  int tcum = 0;
  for (int i = 0; i < 11; ++i) {
    mt.src[i] = wsrc[i];
    mt.dst[i] = wdst[i];
    mt.K[i] = wK[i];
    mt.N[i] = wNd[i];
    mt.st[i] = wSt[i];
    mt.co[i] = wCo[i];
    mt.ts[i] = tcum;
    tcum += (wK[i] >> 5) * (wNd[i] >> 5);
  }
  mt.ts[11] = tcum;

  const f16* NH = nullptr;
  const float* NOF = nullptr;
  float* NF = nullptr;
  f16* NHm = nullptr;

  multi_transp<<<tcum, 256, 0, stream>>>(mt);
  cvt_h<<<(5L * NN * F_IN) / 1024, 256, 0, stream>>>(feat, feat16);

  // FEM: fem16 = relu(feat @ W_fem + b)
  hgemm<1, 64, 1><<<dim3(4, 80, 1), 256, 0, stream>>>(
      feat16, NH, F_IN, W_femT, b_fem, NF, fem16, NOF, NOF, NHm, NF,
      5 * NN, HF, F_IN);

  // edmT[t] = [fem16[t] | noise[t]]^T   [384,2048]
  transp_to_h<f16><<<dim3(8, 64, 4), 256, 0, stream>>>(
      fem16, edmT, NN, HF, (long)NN * HF, (long)G_IN * NN);
  transp_to_h<float><<<dim3(4, 64, 4), 256, 0, stream>>>(
      noise, edmT + (long)HF * NN, NN, DZ, (long)NN * DZ, (long)G_IN * NN);

  // fused sup path -> g16
  sup_gnn<<<dim3(64, 4, 1), 256, 0, stream>>>(sup, edmT, W_gnnT, b_gnn, g16);

  // fm16 = fem @ W_att + b
  hgemm<0, 64, 1><<<dim3(4, 80, 1), 256, 0, stream>>>(
      fem16, NH, HF, W_attT, b_att, NF, fm16, NOF, NOF, NHm, NF,
      5 * NN, HH, HF);

  hipMemsetAsync(hA, 0, (long)NN * HH * 4, stream);
  hipMemsetAsync(h16A, 0, (long)NN * HH * 2, stream);

  float* hcur = hA; float* hnext = hB;
  f16* h16cur = h16A; f16* h16next = h16B;
  for (int t = 0; t < T_WIN; ++t) {
    const f16* gt = g16 + (long)t * NN * HH;
    // gates: sigmoid([gt|h]@Wgcat + bg) -> rh16 (r*h), ubuf (u)
    hgemm<4, 64, 0><<<dim3(8, 16, 1), 256, 0, stream>>>(
        gt, h16cur, 256, WgcatT, bg, NF, NHm, hcur, NOF, rh16, ubuf,
        NN, 512, 512);
    // c = tanh([gt|rh]@Wccat + bc); rnn = (1-u)h+uc -> rnnT16 (transposed)
    cgemm_rnnT<<<dim3(4, 16, 1), 256, 0, stream>>>(
        gt, rh16, WccatT, bc, hcur, ubuf, rnnT16);
    // S = fm[t+1] @ fm[t]^T
    hgemm<0, 128, 0><<<dim3(16, 16, 1), 256, 0, stream>>>(
        fm16 + (long)(t + 1) * NN * HH, NH, HH, fm16 + (long)t * NN * HH,
        NOF, Sbuf, NHm, NOF, NOF, NHm, NF, NN, NN, HH);
    softmax_mix<<<NN, 256, 0, stream>>>(Sbuf, align + (long)t * NN * NN,
                                        lambd, M16);
    // h_next = M16 @ rnn
    hgemm<0, 64, 2><<<dim3(4, 16, 1), 256, 0, stream>>>(
        M16, NH, NN, rnnT16, NOF, hnext, h16next, NOF, NOF, NHm, NF,
        NN, HH, NN);
    float* tf = hcur; hcur = hnext; hnext = tf;
    f16* th = h16cur; h16cur = h16next; h16next = th;
  }

  // --- EAM -------------------------------------------------------------------
  concat_ecat_h<<<(NN * EIN) / 1024, 256, 0, stream>>>(
      hcur, fem16 + 4L * NN * HF, ecat16);
  hgemm<3, 64, 1><<<dim3(4, 16, 1), 256, 0, stream>>>(
      ecat16, NH, EIN, Wemb1T, b_emb1, NF, e1_16, NOF, NOF, NHm, NF,
      NN, E1D, EIN);
  hgemm<3, 64, 0><<<dim3(1, 16, 1), 256, 0, stream>>>(
      e1_16, NH, E1D, Wemb2T, b_emb2, emb0, NHm, NOF, NOF, NHm, NF,
      NN, E2D, E1D);
  col_l2norm64<<<64, 256, 0, stream>>>(emb0, cn);
  norm_sq64h<<<NN, 64, 0, stream>>>(emb0, cn, emb16, sq);
  hgemm<2, 64, 1><<<dim3(4, 16, 1), 256, 0, stream>>>(
      ecat16, NH, EIN, Wscal1T, b_scal1, NF, s1_16, NOF, NOF, NHm, NF,
      NN, E1D, EIN);
  hgemm<2, 64, 1><<<dim3(1, 16, 1), 256, 0, stream>>>(
      s1_16, NH, E1D, Wscal2T, b_scal2, NF, scal16, NOF, NOF, NHm, NF,
      NN, E2D, E1D);

  pq_decode<<<dim3(16, 16, 1), 256, 0, stream>>>(emb16, scal16, sq,
                                                 (float*)d_out);
}

// Round 4
// 420.879 us; speedup vs baseline: 3.8293x; 1.1593x over previous
//
#include <hip/hip_runtime.h>
#include <math.h>

// ---------------------------------------------------------------------------
// GenNet_tanh forward, round 4: restore parallelism.
//  - sup path: sup_agg (512 blocks, f16 partials) + gnn_l2 (256 blocks, fused
//    partial-sum + GEMM + relu + row-L2norm)
//  - apply GEMM (M16@rnn): K-split x4 via grid.z into f32 partials + hsum4
//  - generalized hgemm (lda/ldb/ldc + z strides)
// ---------------------------------------------------------------------------

#define T_WIN 4
#define NN 2048
#define F_IN 128
#define HF 256
#define HH 256
#define DZ 128
#define G_IN 384
#define EIN 512
#define E1D 256
#define E2D 64

typedef _Float16 f16;
typedef _Float16 f16x8 __attribute__((ext_vector_type(8)));
typedef _Float16 f16x4 __attribute__((ext_vector_type(4)));
typedef float f32x4 __attribute__((ext_vector_type(4)));

__device__ __forceinline__ float wave_sum(float v) {
#pragma unroll
  for (int o = 32; o > 0; o >>= 1) v += __shfl_down(v, o);
  return v;
}
__device__ __forceinline__ float wave_max(float v) {
#pragma unroll
  for (int o = 32; o > 0; o >>= 1) v = fmaxf(v, __shfl_down(v, o));
  return v;
}

__device__ __forceinline__ void gld_lds16(const void* g, void* l) {
  __builtin_amdgcn_global_load_lds(
      (const __attribute__((address_space(1))) unsigned int*)g,
      (__attribute__((address_space(3))) unsigned int*)l, 16, 0, 0);
}

// ---------------------------------------------------------------------------
// fp16 MFMA GEMM, 128 x BN tile, BK=64, 256 threads (4 waves 2x2).
// A: [.,lda] row-major; dual-source: k<kspl from A, else from A2 (lda2).
// BT: [N,ldb] row-major (B transposed).  C index: r*ldc + cc.
// blockIdx.z advances A/BT/Cf/Ch by zA/zB/zC elements (batch or K-split).
// EPI: 0 none, 1 relu, 2 sigmoid, 3 tanh, 4 GRU-gates.  WOUT: 0 f32, 1 f16.
// ---------------------------------------------------------------------------
template <int EPI, int BN, int WOUT>
__global__ __launch_bounds__(256) void hgemm(
    const f16* __restrict__ A, const f16* __restrict__ A2,
    const f16* __restrict__ BT, const float* __restrict__ bias,
    float* __restrict__ Cf, f16* __restrict__ Ch,
    const float* __restrict__ X1f, f16* __restrict__ Xrh,
    float* __restrict__ Xu_out, int lda, int lda2, int kspl, int ldb, int ldc,
    int K, long zA, long zB, long zC) {
  constexpr int WN = BN / 2;
  constexpr int FN = WN / 16;
  constexpr int BI = BN / 32;
  __shared__ alignas(16) f16 As[128 * 64];
  __shared__ alignas(16) f16 Bs[BN * 64];
  const int tid = threadIdx.x;
  const int lane = tid & 63, wid = tid >> 6;
  const int wm = wid >> 1, wn = wid & 1;
  const int row0 = blockIdx.y * 128, col0 = blockIdx.x * BN;
  const long zb = blockIdx.z;
  A += zb * zA;
  BT += zb * zB;
  const int l8 = lane >> 3;
  const int lx = ((lane & 7) ^ l8) * 8;  // pre-swizzled source chunk
  const int sw = (lane & 7) * 8;         // frag-read XOR

  f32x4 acc[4][FN];
#pragma unroll
  for (int m = 0; m < 4; ++m)
#pragma unroll
    for (int n = 0; n < FN; ++n) acc[m][n] = (f32x4){0.f, 0.f, 0.f, 0.f};

  for (int k0 = 0; k0 < K; k0 += 64) {
#pragma unroll
    for (int i = 0; i < 4; ++i) {
      int r = wid * 32 + i * 8;
      const f16* src =
          (k0 < kspl) ? A + (size_t)(row0 + r + l8) * lda + k0 + lx
                      : A2 + (size_t)(row0 + r + l8) * lda2 + (k0 - kspl) + lx;
      gld_lds16(src, &As[r * 64]);
    }
#pragma unroll
    for (int i = 0; i < BI; ++i) {
      int r = wid * (BN / 4) + i * 8;
      gld_lds16(BT + (size_t)(col0 + r + l8) * ldb + k0 + lx, &Bs[r * 64]);
    }
    __syncthreads();
#pragma unroll
    for (int ks = 0; ks < 2; ++ks) {
      f16x8 af[4], bf[FN];
#pragma unroll
      for (int m = 0; m < 4; ++m)
        af[m] = *(const f16x8*)&As[((wm * 64 + m * 16 + (lane & 15)) * 64 +
                                    ks * 32 + (lane >> 4) * 8) ^ sw];
#pragma unroll
      for (int n = 0; n < FN; ++n)
        bf[n] = *(const f16x8*)&Bs[((wn * WN + n * 16 + (lane & 15)) * 64 +
                                    ks * 32 + (lane >> 4) * 8) ^ sw];
#pragma unroll
      for (int m = 0; m < 4; ++m)
#pragma unroll
        for (int n = 0; n < FN; ++n)
          acc[m][n] = __builtin_amdgcn_mfma_f32_16x16x32_f16(af[m], bf[n],
                                                             acc[m][n], 0, 0, 0);
    }
    __syncthreads();
  }

  const int cl = lane & 15, rh4 = (lane >> 4) * 4;
  float* Cfb = Cf + zb * zC;
  f16* Chb = Ch + zb * zC;
#pragma unroll
  for (int m = 0; m < 4; ++m) {
#pragma unroll
    for (int n = 0; n < FN; ++n) {
      int cc = col0 + wn * WN + n * 16 + cl;
      float bv = bias ? bias[cc] : 0.f;
#pragma unroll
      for (int q = 0; q < 4; ++q) {
        size_t r = row0 + wm * 64 + m * 16 + rh4 + q;
        float v = acc[m][n][q] + bv;
        if (EPI == 4) {
          float sv = 1.f / (1.f + __expf(-v));
          if (cc < 256)
            Xrh[r * 256 + cc] = (f16)(sv * X1f[r * 256 + cc]);
          else
            Xu_out[r * 256 + cc - 256] = sv;
        } else {
          if (EPI == 1) v = fmaxf(v, 0.f);
          if (EPI == 2) v = 1.f / (1.f + __expf(-v));
          if (EPI == 3) v = tanhf(v);
          if (WOUT == 0) Cfb[r * ldc + cc] = v;
          if (WOUT == 1) Chb[r * ldc + cc] = (f16)v;
        }
      }
    }
  }
}

// ---------------------------------------------------------------------------
// sup_agg: aggP[kh][t][m][c] = sum_{k in half kh} sup[t][m][k]*edm[t][k][c]
// block = 32 rows x 384 cols x K-half 1024.  grid (64, 2, 4).  f16 partials.
// ---------------------------------------------------------------------------
__global__ __launch_bounds__(256) void sup_agg(
    const float* __restrict__ sup, const f16* __restrict__ edmT,
    f16* __restrict__ aggP) {
  __shared__ alignas(16) f16 As[32 * 64];
  __shared__ alignas(16) f16 Bs[384 * 64];
  const int tid = threadIdx.x;
  const int lane = tid & 63, wid = tid >> 6;
  const int m0 = blockIdx.x * 32, kh = blockIdx.y, t = blockIdx.z;
  const int l8 = lane >> 3;
  const int lx = ((lane & 7) ^ l8) * 8;
  const int sw = (lane & 7) * 8;
  const int cl = lane & 15, hi = lane >> 4;
  const float* supT = sup + (size_t)t * NN * NN;
  const f16* edmTt = edmT + (size_t)t * G_IN * NN;

  f32x4 acc[2][6];
#pragma unroll
  for (int m = 0; m < 2; ++m)
#pragma unroll
    for (int n = 0; n < 6; ++n) acc[m][n] = (f32x4){0.f, 0.f, 0.f, 0.f};

  const int ar = tid >> 3;
  const int acw = ((tid & 7) ^ (ar & 7)) * 8;

  const int kbeg = kh * 1024;
  for (int k0 = kbeg; k0 < kbeg + 1024; k0 += 64) {
    const float* ap = supT + (size_t)(m0 + ar) * NN + k0 + ((tid & 7) * 8);
    float4 f0 = *(const float4*)ap;
    float4 f1 = *(const float4*)(ap + 4);
    f16x8 hv = {(f16)f0.x, (f16)f0.y, (f16)f0.z, (f16)f0.w,
                (f16)f1.x, (f16)f1.y, (f16)f1.z, (f16)f1.w};
    *(f16x8*)&As[ar * 64 + acw] = hv;
#pragma unroll
    for (int i = 0; i < 12; ++i) {
      int rn = wid * 96 + i * 8;
      gld_lds16(edmTt + (size_t)(rn + l8) * NN + k0 + lx, &Bs[rn * 64]);
    }
    __syncthreads();
#pragma unroll
    for (int ks = 0; ks < 2; ++ks) {
      f16x8 af[2], bf[6];
#pragma unroll
      for (int m = 0; m < 2; ++m)
        af[m] = *(const f16x8*)&As[((m * 16 + cl) * 64 + ks * 32 + hi * 8) ^ sw];
#pragma unroll
      for (int n = 0; n < 6; ++n)
        bf[n] = *(const f16x8*)&Bs[((wid * 96 + n * 16 + cl) * 64 + ks * 32 +
                                    hi * 8) ^ sw];
#pragma unroll
      for (int m = 0; m < 2; ++m)
#pragma unroll
        for (int n = 0; n < 6; ++n)
          acc[m][n] = __builtin_amdgcn_mfma_f32_16x16x32_f16(af[m], bf[n],
                                                             acc[m][n], 0, 0, 0);
    }
    __syncthreads();
  }

  f16* dst = aggP + (size_t)kh * (4L * NN * G_IN) +
             ((size_t)t * NN + m0) * G_IN;
#pragma unroll
  for (int m = 0; m < 2; ++m)
#pragma unroll
    for (int n = 0; n < 6; ++n)
#pragma unroll
      for (int q = 0; q < 4; ++q)
        dst[(size_t)(m * 16 + hi * 4 + q) * G_IN + wid * 96 + n * 16 + cl] =
            (f16)acc[m][n][q];
}

// ---------------------------------------------------------------------------
// gnn_l2: g16[r] = l2norm(relu((aggP0[r]+aggP1[r]) @ Wgnn + b)), r in [0,8192)
// block = 32 rows x all 256 cols.  grid 256.
// ---------------------------------------------------------------------------
__global__ __launch_bounds__(256) void gnn_l2(
    const f16* __restrict__ aggP, const f16* __restrict__ WgnnT,
    const float* __restrict__ bgnn, f16* __restrict__ g16) {
  __shared__ alignas(16) f16 As[32 * 64];
  __shared__ alignas(16) f16 Bs[256 * 64];
  __shared__ float red[4][32];
  const int tid = threadIdx.x;
  const int lane = tid & 63, wid = tid >> 6;
  const int m0 = blockIdx.x * 32;
  const int l8 = lane >> 3;
  const int lx = ((lane & 7) ^ l8) * 8;
  const int sw = (lane & 7) * 8;
  const int cl = lane & 15, hi = lane >> 4;
  const f16* p0 = aggP;
  const f16* p1 = aggP + 4L * NN * G_IN;

  f32x4 acc[2][4];
#pragma unroll
  for (int m = 0; m < 2; ++m)
#pragma unroll
    for (int n = 0; n < 4; ++n) acc[m][n] = (f32x4){0.f, 0.f, 0.f, 0.f};

  const int ar = tid >> 3;
  const int acw = ((tid & 7) ^ (ar & 7)) * 8;

  for (int k0 = 0; k0 < G_IN; k0 += 64) {
    size_t gi = (size_t)(m0 + ar) * G_IN + k0 + ((tid & 7) * 8);
    f16x8 a0 = *(const f16x8*)(p0 + gi);
    f16x8 a1 = *(const f16x8*)(p1 + gi);
    *(f16x8*)&As[ar * 64 + acw] = a0 + a1;
#pragma unroll
    for (int i = 0; i < 8; ++i) {
      int rn = wid * 64 + i * 8;
      gld_lds16(WgnnT + (size_t)(rn + l8) * G_IN + k0 + lx, &Bs[rn * 64]);
    }
    __syncthreads();
#pragma unroll
    for (int ks = 0; ks < 2; ++ks) {
      f16x8 af[2], bf[4];
#pragma unroll
      for (int m = 0; m < 2; ++m)
        af[m] = *(const f16x8*)&As[((m * 16 + cl) * 64 + ks * 32 + hi * 8) ^ sw];
#pragma unroll
      for (int n = 0; n < 4; ++n)
        bf[n] = *(const f16x8*)&Bs[((wid * 64 + n * 16 + cl) * 64 + ks * 32 +
                                    hi * 8) ^ sw];
#pragma unroll
      for (int m = 0; m < 2; ++m)
#pragma unroll
        for (int n = 0; n < 4; ++n)
          acc[m][n] = __builtin_amdgcn_mfma_f32_16x16x32_f16(af[m], bf[n],
                                                             acc[m][n], 0, 0, 0);
    }
    __syncthreads();
  }

#pragma unroll
  for (int m = 0; m < 2; ++m)
#pragma unroll
    for (int n = 0; n < 4; ++n) {
      float bv = bgnn[wid * 64 + n * 16 + cl];
#pragma unroll
      for (int q = 0; q < 4; ++q)
        acc[m][n][q] = fmaxf(acc[m][n][q] + bv, 0.f);
    }
#pragma unroll
  for (int m = 0; m < 2; ++m)
#pragma unroll
    for (int q = 0; q < 4; ++q) {
      float ss = 0.f;
#pragma unroll
      for (int n = 0; n < 4; ++n) ss += acc[m][n][q] * acc[m][n][q];
#pragma unroll
      for (int msk = 1; msk < 16; msk <<= 1) ss += __shfl_xor(ss, msk);
      if (cl == 0) red[wid][m * 16 + hi * 4 + q] = ss;
    }
  __syncthreads();
#pragma unroll
  for (int m = 0; m < 2; ++m)
#pragma unroll
    for (int q = 0; q < 4; ++q) {
      int row = m * 16 + hi * 4 + q;
      float tot = red[0][row] + red[1][row] + red[2][row] + red[3][row];
      float inv = 1.f / fmaxf(sqrtf(tot), 1e-12f);
#pragma unroll
      for (int n = 0; n < 4; ++n)
        g16[(size_t)(m0 + row) * 256 + wid * 64 + n * 16 + cl] =
            (f16)(acc[m][n][q] * inv);
    }
}

// --- sum 4 K-split partials -> h f32 + f16 -----------------------------------
__global__ __launch_bounds__(256) void hsum4(const float* __restrict__ hP,
                                             float* __restrict__ hf,
                                             f16* __restrict__ h16) {
  long i = ((long)blockIdx.x * 256 + threadIdx.x) * 4;
  float4 a = *(const float4*)(hP + i);
  float4 b = *(const float4*)(hP + 524288 + i);
  float4 c = *(const float4*)(hP + 1048576 + i);
  float4 d = *(const float4*)(hP + 1572864 + i);
  float4 s = {a.x + b.x + c.x + d.x, a.y + b.y + c.y + d.y,
              a.z + b.z + c.z + d.z, a.w + b.w + c.w + d.w};
  *(float4*)(hf + i) = s;
  f16x4 o = {(f16)s.x, (f16)s.y, (f16)s.z, (f16)s.w};
  *(f16x4*)(h16 + i) = o;
}

// ---------------------------------------------------------------------------
// Candidate GEMM + GRU mix + transposed write (unchanged from R3)
// ---------------------------------------------------------------------------
__global__ __launch_bounds__(256) void cgemm_rnnT(
    const f16* __restrict__ A, const f16* __restrict__ A2,
    const f16* __restrict__ BT, const float* __restrict__ bias,
    const float* __restrict__ hf, const float* __restrict__ ubuf,
    f16* __restrict__ rnnT) {
  constexpr int K = 512, kspl = 256;
  __shared__ alignas(16) f16 As[128 * 64];
  __shared__ alignas(16) f16 Bs[64 * 64];
  __shared__ alignas(16) f16 tileT[64 * 136];
  const int tid = threadIdx.x;
  const int lane = tid & 63, wid = tid >> 6;
  const int wm = wid >> 1, wn = wid & 1;
  const int row0 = blockIdx.y * 128, col0 = blockIdx.x * 64;
  const int l8 = lane >> 3;
  const int lx = ((lane & 7) ^ l8) * 8;
  const int sw = (lane & 7) * 8;

  f32x4 acc[4][2];
#pragma unroll
  for (int m = 0; m < 4; ++m)
#pragma unroll
    for (int n = 0; n < 2; ++n) acc[m][n] = (f32x4){0.f, 0.f, 0.f, 0.f};

  for (int k0 = 0; k0 < K; k0 += 64) {
#pragma unroll
    for (int i = 0; i < 4; ++i) {
      int r = wid * 32 + i * 8;
      const f16* src =
          (k0 < kspl) ? A + (size_t)(row0 + r + l8) * 256 + k0 + lx
                      : A2 + (size_t)(row0 + r + l8) * 256 + (k0 - 256) + lx;
      gld_lds16(src, &As[r * 64]);
    }
#pragma unroll
    for (int i = 0; i < 2; ++i) {
      int r = wid * 16 + i * 8;
      gld_lds16(BT + (size_t)(col0 + r + l8) * K + k0 + lx, &Bs[r * 64]);
    }
    __syncthreads();
#pragma unroll
    for (int ks = 0; ks < 2; ++ks) {
      f16x8 af[4], bf[2];
#pragma unroll
      for (int m = 0; m < 4; ++m)
        af[m] = *(const f16x8*)&As[((wm * 64 + m * 16 + (lane & 15)) * 64 +
                                    ks * 32 + (lane >> 4) * 8) ^ sw];
#pragma unroll
      for (int n = 0; n < 2; ++n)
        bf[n] = *(const f16x8*)&Bs[((wn * 32 + n * 16 + (lane & 15)) * 64 +
                                    ks * 32 + (lane >> 4) * 8) ^ sw];
#pragma unroll
      for (int m = 0; m < 4; ++m)
#pragma unroll
        for (int n = 0; n < 2; ++n)
          acc[m][n] = __builtin_amdgcn_mfma_f32_16x16x32_f16(af[m], bf[n],
                                                             acc[m][n], 0, 0, 0);
    }
    __syncthreads();
  }

  const int cl = lane & 15, rh4 = (lane >> 4) * 4;
#pragma unroll
  for (int m = 0; m < 4; ++m) {
#pragma unroll
    for (int n = 0; n < 2; ++n) {
      int ccl = wn * 32 + n * 16 + cl;
      int cc = col0 + ccl;
      float bv = bias[cc];
#pragma unroll
      for (int q = 0; q < 4; ++q) {
        int rl = wm * 64 + m * 16 + rh4 + q;
        size_t r = row0 + rl;
        float c = tanhf(acc[m][n][q] + bv);
        float u = ubuf[r * 256 + cc];
        float h = hf[r * 256 + cc];
        tileT[ccl * 136 + rl] = (f16)((1.f - u) * h + u * c);
      }
    }
  }
  __syncthreads();
#pragma unroll
  for (int i = 0; i < 4; ++i) {
    int chunk = i * 256 + tid;
    int rr = chunk >> 4, seg = (chunk & 15) * 8;
    *(f16x8*)&rnnT[(size_t)(col0 + rr) * NN + row0 + seg] =
        *(const f16x8*)&tileT[rr * 136 + seg];
  }
}

// ---------------------------------------------------------------------------
// Fused P/Q/decode (unchanged from R3)
// ---------------------------------------------------------------------------
__global__ __launch_bounds__(256) void pq_decode(
    const f16* __restrict__ emb, const f16* __restrict__ scal,
    const float* __restrict__ sq, float* __restrict__ out) {
  __shared__ alignas(16) f16 EA[128 * 64], EB[128 * 64], SA[128 * 64],
      SB[128 * 64];
  const int tid = threadIdx.x;
  const int lane = tid & 63, wid = tid >> 6;
  const int wm = wid >> 1, wn = wid & 1;
  const int row0 = blockIdx.y * 128, col0 = blockIdx.x * 128;
  const int l8 = lane >> 3;
  const int lx = ((lane & 7) ^ l8) * 8;
  const int sw = (lane & 7) * 8;
#pragma unroll
  for (int i = 0; i < 2; ++i) {
    int r = wid * 16 + i * 8;
    gld_lds16(emb + (size_t)(row0 + r + l8) * 64 + lx, &EA[r * 64]);
    gld_lds16(emb + (size_t)(col0 + r + l8) * 64 + lx, &EB[r * 64]);
    gld_lds16(scal + (size_t)(row0 + r + l8) * 64 + lx, &SA[r * 64]);
    gld_lds16(scal + (size_t)(col0 + r + l8) * 64 + lx, &SB[r * 64]);
    int r2 = r + 64;
    gld_lds16(emb + (size_t)(row0 + r2 + l8) * 64 + lx, &EA[r2 * 64]);
    gld_lds16(emb + (size_t)(col0 + r2 + l8) * 64 + lx, &EB[r2 * 64]);
    gld_lds16(scal + (size_t)(row0 + r2 + l8) * 64 + lx, &SA[r2 * 64]);
    gld_lds16(scal + (size_t)(col0 + r2 + l8) * 64 + lx, &SB[r2 * 64]);
  }
  __syncthreads();
  f32x4 accP[4][4], accQ[4][4];
#pragma unroll
  for (int m = 0; m < 4; ++m)
#pragma unroll
    for (int n = 0; n < 4; ++n) {
      accP[m][n] = (f32x4){0.f, 0.f, 0.f, 0.f};
      accQ[m][n] = (f32x4){0.f, 0.f, 0.f, 0.f};
    }
#pragma unroll
  for (int ks = 0; ks < 2; ++ks) {
    f16x8 af[4], bf[4];
#pragma unroll
    for (int m = 0; m < 4; ++m)
      af[m] = *(const f16x8*)&EA[((wm * 64 + m * 16 + (lane & 15)) * 64 +
                                  ks * 32 + (lane >> 4) * 8) ^ sw];
#pragma unroll
    for (int n = 0; n < 4; ++n)
      bf[n] = *(const f16x8*)&EB[((wn * 64 + n * 16 + (lane & 15)) * 64 +
                                  ks * 32 + (lane >> 4) * 8) ^ sw];
#pragma unroll
    for (int m = 0; m < 4; ++m)
#pragma unroll
      for (int n = 0; n < 4; ++n)
        accP[m][n] = __builtin_amdgcn_mfma_f32_16x16x32_f16(af[m], bf[n],
                                                            accP[m][n], 0, 0, 0);
#pragma unroll
    for (int m = 0; m < 4; ++m)
      af[m] = *(const f16x8*)&SA[((wm * 64 + m * 16 + (lane & 15)) * 64 +
                                  ks * 32 + (lane >> 4) * 8) ^ sw];
#pragma unroll
    for (int n = 0; n < 4; ++n)
      bf[n] = *(const f16x8*)&SB[((wn * 64 + n * 16 + (lane & 15)) * 64 +
                                  ks * 32 + (lane >> 4) * 8) ^ sw];
#pragma unroll
    for (int m = 0; m < 4; ++m)
#pragma unroll
      for (int n = 0; n < 4; ++n)
        accQ[m][n] = __builtin_amdgcn_mfma_f32_16x16x32_f16(af[m], bf[n],
                                                            accQ[m][n], 0, 0, 0);
  }
  const int cl = lane & 15, rh4 = (lane >> 4) * 4;
#pragma unroll
  for (int m = 0; m < 4; ++m) {
#pragma unroll
    for (int n = 0; n < 4; ++n) {
      int c = col0 + wn * 64 + n * 16 + cl;
      float sqc = sq[c];
#pragma unroll
      for (int q = 0; q < 4; ++q) {
        size_t r = row0 + wm * 64 + m * 16 + rh4 + q;
        float dist = -(sq[r] + sqc - 2.f * accP[m][n][q]);
        out[r * NN + c] = 1.f + tanhf(dist * accQ[m][n][q]);
      }
    }
  }
}

// --- fused transpose+convert of the weight matrices --------------------------
struct MT {
  const float* src[11];
  f16* dst[11];
  int K[11], N[11], st[11], co[11], ts[12];
};
__global__ __launch_bounds__(256) void multi_transp(MT mt) {
  __shared__ float tile[32][33];
  int b = blockIdx.x, w = 0;
  while (b >= mt.ts[w + 1]) ++w;
  int lt = b - mt.ts[w];
  int K = mt.K[w], N = mt.N[w];
  int tk = lt % (K >> 5), tn = lt / (K >> 5);
  int k0 = tk * 32, n0 = tn * 32;
  int tx = threadIdx.x & 31, ty = threadIdx.x >> 5;
  const float* src = mt.src[w];
#pragma unroll
  for (int i = 0; i < 32; i += 8)
    tile[ty + i][tx] = src[(size_t)(k0 + ty + i) * N + n0 + tx];
  __syncthreads();
  f16* dst = mt.dst[w];
  int st = mt.st[w], co = mt.co[w];
#pragma unroll
  for (int i = 0; i < 32; i += 8)
    dst[(size_t)(n0 + ty + i) * st + co + k0 + tx] = (f16)tile[tx][ty + i];
}

// --- generic batched tiled transpose -> fp16 ---------------------------------
template <typename TIN>
__global__ __launch_bounds__(256) void transp_to_h(
    const TIN* __restrict__ in, f16* __restrict__ out, int R, int C, long sIn,
    long sOut) {
  in += blockIdx.z * sIn;
  out += blockIdx.z * sOut;
  __shared__ float tile[32][33];
  int c0 = blockIdx.x * 32, r0 = blockIdx.y * 32;
  int tx = threadIdx.x & 31, ty = threadIdx.x >> 5;
#pragma unroll
  for (int i = 0; i < 32; i += 8)
    tile[ty + i][tx] = (float)in[(size_t)(r0 + ty + i) * C + c0 + tx];
  __syncthreads();
#pragma unroll
  for (int i = 0; i < 32; i += 8)
    out[(size_t)(c0 + ty + i) * R + r0 + tx] = (f16)tile[tx][ty + i];
}

// --- f32 -> fp16 convert -----------------------------------------------------
__global__ __launch_bounds__(256) void cvt_h(const float* __restrict__ in,
                                             f16* __restrict__ out) {
  long i = ((long)blockIdx.x * 256 + threadIdx.x) * 4;
  float4 v = *(const float4*)(in + i);
  f16x4 o = {(f16)v.x, (f16)v.y, (f16)v.z, (f16)v.w};
  *(f16x4*)(out + i) = o;
}

// --- row softmax + mix with align -> fp16 ------------------------------------
__global__ __launch_bounds__(256) void softmax_mix(
    const float* __restrict__ S, const float* __restrict__ Al,
    const float* __restrict__ lam_ptr, f16* __restrict__ Mh) {
  const int tid = threadIdx.x;
  const float4* s4 = (const float4*)(S + (long)blockIdx.x * 2048);
  float4 a = s4[tid], b = s4[tid + 256];
  float m = fmaxf(fmaxf(fmaxf(a.x, a.y), fmaxf(a.z, a.w)),
                  fmaxf(fmaxf(b.x, b.y), fmaxf(b.z, b.w)));
  __shared__ float red[4];
  float w = wave_max(m);
  if ((tid & 63) == 0) red[tid >> 6] = w;
  __syncthreads();
  m = fmaxf(fmaxf(red[0], red[1]), fmaxf(red[2], red[3]));
  __syncthreads();
  a.x = __expf(a.x - m); a.y = __expf(a.y - m);
  a.z = __expf(a.z - m); a.w = __expf(a.w - m);
  b.x = __expf(b.x - m); b.y = __expf(b.y - m);
  b.z = __expf(b.z - m); b.w = __expf(b.w - m);
  float s = a.x + a.y + a.z + a.w + b.x + b.y + b.z + b.w;
  w = wave_sum(s);
  if ((tid & 63) == 0) red[tid >> 6] = w;
  __syncthreads();
  float inv = 1.f / (red[0] + red[1] + red[2] + red[3]);
  float lam = lam_ptr[0], oml = 1.f - lam;
  const float4* al4 = (const float4*)(Al + (long)blockIdx.x * 2048);
  float4 x = al4[tid], y = al4[tid + 256];
  f16x4 o0 = {(f16)(lam * x.x + oml * a.x * inv),
              (f16)(lam * x.y + oml * a.y * inv),
              (f16)(lam * x.z + oml * a.z * inv),
              (f16)(lam * x.w + oml * a.w * inv)};
  f16x4 o1 = {(f16)(lam * y.x + oml * b.x * inv),
              (f16)(lam * y.y + oml * b.y * inv),
              (f16)(lam * y.z + oml * b.z * inv),
              (f16)(lam * y.w + oml * b.w * inv)};
  f16x4* out4 = (f16x4*)(Mh + (long)blockIdx.x * 2048);
  out4[tid] = o0;
  out4[tid + 256] = o1;
}

// --- ecat16 = [fp16(h) | fem16[4]] -------------------------------------------
__global__ __launch_bounds__(256) void concat_ecat_h(
    const float* __restrict__ h, const f16* __restrict__ fem4,
    f16* __restrict__ ecat) {
  long i4 = ((long)blockIdx.x * 256 + threadIdx.x) * 4;
  int n = i4 >> 9, f = i4 & 511;
  f16x4 o;
  if (f < 256) {
    float4 v = *(const float4*)(h + (long)n * 256 + f);
    o = (f16x4){(f16)v.x, (f16)v.y, (f16)v.z, (f16)v.w};
  } else {
    o = *(const f16x4*)(fem4 + (long)n * 256 + f - 256);
  }
  *(f16x4*)(ecat + i4) = o;
}

// --- column L2 norms of emb0 [N,64] ------------------------------------------
__global__ __launch_bounds__(256) void col_l2norm64(
    const float* __restrict__ x, float* __restrict__ cn) {
  int c = blockIdx.x;
  float ss = 0.f;
  for (int r = threadIdx.x; r < NN; r += 256) {
    float v = x[(long)r * 64 + c];
    ss += v * v;
  }
  __shared__ float red[4];
  float w = wave_sum(ss);
  if ((threadIdx.x & 63) == 0) red[threadIdx.x >> 6] = w;
  __syncthreads();
  if (threadIdx.x == 0)
    cn[c] = fmaxf(sqrtf(red[0] + red[1] + red[2] + red[3]), 1e-12f);
}

// --- emb16 = emb0/cn ; sq[i] = row sumsq -------------------------------------
__global__ void norm_sq64h(const float* __restrict__ x,
                           const float* __restrict__ cn,
                           f16* __restrict__ emb16, float* __restrict__ sq) {
  int i = blockIdx.x, j = threadIdx.x;
  float e = x[(long)i * 64 + j] / cn[j];
  emb16[(long)i * 64 + j] = (f16)e;
  float s = wave_sum(e * e);
  if (j == 0) sq[i] = s;
}

// ---------------------------------------------------------------------------
extern "C" void kernel_launch(void* const* d_in, const int* in_sizes, int n_in,
                              void* d_out, int out_size, void* d_ws,
                              size_t ws_size, hipStream_t stream) {
  (void)in_sizes; (void)n_in; (void)out_size; (void)ws_size;
  const float* sup    = (const float*)d_in[0];
  const float* feat   = (const float*)d_in[1];
  const float* noise  = (const float*)d_in[2];
  const float* align  = (const float*)d_in[3];
  const float* lambd  = (const float*)d_in[4];
  const float* W_fem  = (const float*)d_in[5];
  const float* b_fem  = (const float*)d_in[6];
  const float* W_gnn  = (const float*)d_in[7];
  const float* b_gnn  = (const float*)d_in[8];
  const float* Wg_x   = (const float*)d_in[9];
  const float* Wg_h   = (const float*)d_in[10];
  const float* bg     = (const float*)d_in[11];
  const float* Wc_x   = (const float*)d_in[12];
  const float* Wc_h   = (const float*)d_in[13];
  const float* bc     = (const float*)d_in[14];
  const float* W_att  = (const float*)d_in[15];
  const float* b_att  = (const float*)d_in[16];
  const float* W_emb1 = (const float*)d_in[17];
  const float* b_emb1 = (const float*)d_in[18];
  const float* W_emb2 = (const float*)d_in[19];
  const float* b_emb2 = (const float*)d_in[20];
  const float* W_scal1= (const float*)d_in[21];
  const float* b_scal1= (const float*)d_in[22];
  const float* W_scal2= (const float*)d_in[23];
  const float* b_scal2= (const float*)d_in[24];

  char* wsb = (char*)d_ws;
  size_t po = 0;
  auto P = [&](size_t bytes) {
    size_t r = po;
    po += (bytes + 255) & ~(size_t)255;
    return r;
  };
  f16* fem16  = (f16*)(wsb + P(5L * NN * HF * 2));
  f16* fm16   = (f16*)(wsb + P(5L * NN * HH * 2));
  f16* g16    = (f16*)(wsb + P(4L * NN * HH * 2));
  f16* WT     = (f16*)(wsb + P(884736L * 2));
  f16* edmT   = (f16*)(wsb + P(4L * G_IN * NN * 2));
  f16* feat16 = (f16*)(wsb + P(5L * NN * F_IN * 2));
  f16* aggP   = (f16*)(wsb + P(2L * 4 * NN * G_IN * 2));
  float* hA   = (float*)(wsb + P((long)NN * HH * 4));
  float* hB   = (float*)(wsb + P((long)NN * HH * 4));
  f16* h16A   = (f16*)(wsb + P((long)NN * HH * 2));
  f16* h16B   = (f16*)(wsb + P((long)NN * HH * 2));
  float* ubuf = (float*)(wsb + P((long)NN * HH * 4));
  f16* rh16   = (f16*)(wsb + P((long)NN * HH * 2));
  f16* rnnT16 = (f16*)(wsb + P((long)NN * HH * 2));
  float* hP   = (float*)(wsb + P(4L * NN * HH * 4));
  float* Sbuf = (float*)(wsb + P((long)NN * NN * 4));
  f16* M16    = (f16*)(wsb + P((long)NN * NN * 2));
  f16* ecat16 = (f16*)(wsb + P((long)NN * EIN * 2));
  f16* e1_16  = (f16*)(wsb + P((long)NN * E1D * 2));
  float* emb0 = (float*)(wsb + P((long)NN * E2D * 4));
  f16* emb16  = (f16*)(wsb + P((long)NN * E2D * 2));
  f16* s1_16  = (f16*)(wsb + P((long)NN * E1D * 2));
  f16* scal16 = (f16*)(wsb + P((long)NN * E2D * 2));
  float* cn   = (float*)(wsb + P(64 * 4));
  float* sq   = (float*)(wsb + P(NN * 4));

  // --- weight transpose/cat table --------------------------------------------
  f16* W_femT  = WT;
  f16* W_gnnT  = W_femT + 32768;
  f16* WgcatT  = W_gnnT + 98304;
  f16* WccatT  = WgcatT + 262144;
  f16* W_attT  = WccatT + 131072;
  f16* Wemb1T  = W_attT + 65536;
  f16* Wemb2T  = Wemb1T + 131072;
  f16* Wscal1T = Wemb2T + 16384;
  f16* Wscal2T = Wscal1T + 131072;

  MT mt;
  const float* wsrc[11] = {W_fem, W_gnn, Wg_x, Wg_h, Wc_x, Wc_h,
                           W_att, W_emb1, W_emb2, W_scal1, W_scal2};
  f16* wdst[11] = {W_femT, W_gnnT, WgcatT, WgcatT, WccatT, WccatT,
                   W_attT, Wemb1T, Wemb2T, Wscal1T, Wscal2T};
  const int wK[11] = {128, 384, 256, 256, 256, 256, 256, 512, 256, 512, 256};
  const int wNd[11] = {256, 256, 512, 512, 256, 256, 256, 256, 64, 256, 64};
  const int wSt[11] = {128, 384, 512, 512, 512, 512, 256, 512, 256, 512, 256};
  const int wCo[11] = {0, 0, 0, 256, 0, 256, 0, 0, 0, 0, 0};
  int tcum = 0;
  for (int i = 0; i < 11; ++i) {
    mt.src[i] = wsrc[i];
    mt.dst[i] = wdst[i];
    mt.K[i] = wK[i];
    mt.N[i] = wNd[i];
    mt.st[i] = wSt[i];
    mt.co[i] = wCo[i];
    mt.ts[i] = tcum;
    tcum += (wK[i] >> 5) * (wNd[i] >> 5);
  }
  mt.ts[11] = tcum;

  const f16* NH = nullptr;
  const float* NOF = nullptr;
  float* NF = nullptr;
  f16* NHm = nullptr;

  multi_transp<<<tcum, 256, 0, stream>>>(mt);
  cvt_h<<<(5L * NN * F_IN) / 1024, 256, 0, stream>>>(feat, feat16);

  // FEM: fem16 = relu(feat @ W_fem + b)
  hgemm<1, 64, 1><<<dim3(4, 80, 1), 256, 0, stream>>>(
      feat16, NH, W_femT, b_fem, NF, fem16, NOF, NHm, NF,
      128, 0, 128, 128, 256, 128, 0, 0, 0);

  // edmT[t] = [fem16[t] | noise[t]]^T   [384,2048]
  transp_to_h<f16><<<dim3(8, 64, 4), 256, 0, stream>>>(
      fem16, edmT, NN, HF, (long)NN * HF, (long)G_IN * NN);
  transp_to_h<float><<<dim3(4, 64, 4), 256, 0, stream>>>(
      noise, edmT + (long)HF * NN, NN, DZ, (long)NN * DZ, (long)G_IN * NN);

  // sup path: partial aggregation + fused gnn/l2norm
  sup_agg<<<dim3(64, 2, 4), 256, 0, stream>>>(sup, edmT, aggP);
  gnn_l2<<<256, 256, 0, stream>>>(aggP, W_gnnT, b_gnn, g16);

  // fm16 = fem @ W_att + b
  hgemm<0, 64, 1><<<dim3(4, 80, 1), 256, 0, stream>>>(
      fem16, NH, W_attT, b_att, NF, fm16, NOF, NHm, NF,
      256, 0, 256, 256, 256, 256, 0, 0, 0);

  hipMemsetAsync(hA, 0, (long)NN * HH * 4, stream);
  hipMemsetAsync(h16A, 0, (long)NN * HH * 2, stream);

  float* hcur = hA; float* hnext = hB;
  f16* h16cur = h16A; f16* h16next = h16B;
  for (int t = 0; t < T_WIN; ++t) {
    const f16* gt = g16 + (long)t * NN * HH;
    // gates: sigmoid([gt|h]@Wgcat + bg) -> rh16 (r*h), ubuf (u)
    hgemm<4, 64, 0><<<dim3(8, 16, 1), 256, 0, stream>>>(
        gt, h16cur, WgcatT, bg, NF, NHm, hcur, rh16, ubuf,
        256, 256, 256, 512, 512, 512, 0, 0, 0);
    // c = tanh([gt|rh]@Wccat + bc); rnn = (1-u)h+uc -> rnnT16 (transposed)
    cgemm_rnnT<<<dim3(4, 16, 1), 256, 0, stream>>>(
        gt, rh16, WccatT, bc, hcur, ubuf, rnnT16);
    // S = fm[t+1] @ fm[t]^T
    hgemm<0, 128, 0><<<dim3(16, 16, 1), 256, 0, stream>>>(
        fm16 + (long)(t + 1) * NN * HH, NH, fm16 + (long)t * NN * HH, NOF,
        Sbuf, NHm, NOF, NHm, NF, 256, 0, 256, 256, 2048, 256, 0, 0, 0);
    softmax_mix<<<NN, 256, 0, stream>>>(Sbuf, align + (long)t * NN * NN,
                                        lambd, M16);
    // h_next partials = M16 @ rnn  (K-split x4 via grid.z)
    hgemm<0, 64, 0><<<dim3(4, 16, 4), 256, 0, stream>>>(
        M16, NH, rnnT16, NOF, hP, NHm, NOF, NHm, NF,
        2048, 0, 512, 2048, 256, 512, 512, 512, 524288);
    hsum4<<<512, 256, 0, stream>>>(hP, hnext, h16next);
    float* tf = hcur; hcur = hnext; hnext = tf;
    f16* th = h16cur; h16cur = h16next; h16next = th;
  }

  // --- EAM -------------------------------------------------------------------
  concat_ecat_h<<<(NN * EIN) / 1024, 256, 0, stream>>>(
      hcur, fem16 + 4L * NN * HF, ecat16);
  hgemm<3, 64, 1><<<dim3(4, 16, 1), 256, 0, stream>>>(
      ecat16, NH, Wemb1T, b_emb1, NF, e1_16, NOF, NHm, NF,
      512, 0, 512, 512, 256, 512, 0, 0, 0);
  hgemm<3, 64, 0><<<dim3(1, 16, 1), 256, 0, stream>>>(
      e1_16, NH, Wemb2T, b_emb2, emb0, NHm, NOF, NHm, NF,
      256, 0, 256, 256, 64, 256, 0, 0, 0);
  col_l2norm64<<<64, 256, 0, stream>>>(emb0, cn);
  norm_sq64h<<<NN, 64, 0, stream>>>(emb0, cn, emb16, sq);
  hgemm<2, 64, 1><<<dim3(4, 16, 1), 256, 0, stream>>>(
      ecat16, NH, Wscal1T, b_scal1, NF, s1_16, NOF, NHm, NF,
      512, 0, 512, 512, 256, 512, 0, 0, 0);
  hgemm<2, 64, 1><<<dim3(1, 16, 1), 256, 0, stream>>>(
      s1_16, NH, Wscal2T, b_scal2, NF, scal16, NOF, NHm, NF,
      256, 0, 256, 256, 64, 256, 0, 0, 0);

  pq_decode<<<dim3(16, 16, 1), 256, 0, stream>>>(emb16, scal16, sq,
                                                 (float*)d_out);
}

// Round 5
// 372.280 us; speedup vs baseline: 4.3292x; 1.1305x over previous
//
#include <hip/hip_runtime.h>
#include <math.h>

// ---------------------------------------------------------------------------
// GenNet_tanh forward, round 5: sup_agg 64x384 tile (48 MFMA/wave/kstep),
// hoisted Xg/Xc pre-activations, paired-batch S+softmax, t0 shortcut,
// fused EAM tail.  32 dispatches.
// ---------------------------------------------------------------------------

#define T_WIN 4
#define NN 2048
#define F_IN 128
#define HF 256
#define HH 256
#define DZ 128
#define G_IN 384
#define EIN 512
#define E1D 256
#define E2D 64

typedef _Float16 f16;
typedef _Float16 f16x8 __attribute__((ext_vector_type(8)));
typedef _Float16 f16x4 __attribute__((ext_vector_type(4)));
typedef float f32x4 __attribute__((ext_vector_type(4)));

__device__ __forceinline__ float wave_sum(float v) {
#pragma unroll
  for (int o = 32; o > 0; o >>= 1) v += __shfl_down(v, o);
  return v;
}
__device__ __forceinline__ float wave_max(float v) {
#pragma unroll
  for (int o = 32; o > 0; o >>= 1) v = fmaxf(v, __shfl_down(v, o));
  return v;
}

__device__ __forceinline__ void gld_lds16(const void* g, void* l) {
  __builtin_amdgcn_global_load_lds(
      (const __attribute__((address_space(1))) unsigned int*)g,
      (__attribute__((address_space(3))) unsigned int*)l, 16, 0, 0);
}

// ---------------------------------------------------------------------------
// fp16 MFMA GEMM, 128 x BN tile, BK=64, 256 threads (4 waves 2x2).
// A: [.,lda] row-major; dual-source: k<kspl from A, else A2 (lda2).
// BT: [N,ldb] row-major.  C index: r*ldc + cc.  grid.z advances by zA/zB/zC.
// EPI: 0 none, 1 relu, 4 GRU-gates(+Xpre), 5 z-sel tanh/sig, 6 col-sel.
// WOUT: 0 f32, 1 f16, 2 both.
// ---------------------------------------------------------------------------
template <int EPI, int BN, int WOUT>
__global__ __launch_bounds__(256) void hgemm(
    const f16* __restrict__ A, const f16* __restrict__ A2,
    const f16* __restrict__ BT, const float* __restrict__ bias,
    const float* __restrict__ bias2, float* __restrict__ Cf,
    f16* __restrict__ Ch, const float* __restrict__ X1f,
    f16* __restrict__ Xrh, float* __restrict__ Xu_out,
    const f16* __restrict__ Xpre, int lda, int lda2, int kspl, int ldb,
    int ldc, int K, long zA, long zB, long zC) {
  constexpr int WN = BN / 2;
  constexpr int FN = WN / 16;
  constexpr int BI = BN / 32;
  __shared__ alignas(16) f16 As[128 * 64];
  __shared__ alignas(16) f16 Bs[BN * 64];
  const int tid = threadIdx.x;
  const int lane = tid & 63, wid = tid >> 6;
  const int wm = wid >> 1, wn = wid & 1;
  const int row0 = blockIdx.y * 128, col0 = blockIdx.x * BN;
  const long zb = blockIdx.z;
  A += zb * zA;
  BT += zb * zB;
  const int l8 = lane >> 3;
  const int lx = ((lane & 7) ^ l8) * 8;  // pre-swizzled source chunk
  const int sw = (lane & 7) * 8;         // frag-read XOR

  f32x4 acc[4][FN];
#pragma unroll
  for (int m = 0; m < 4; ++m)
#pragma unroll
    for (int n = 0; n < FN; ++n) acc[m][n] = (f32x4){0.f, 0.f, 0.f, 0.f};

  for (int k0 = 0; k0 < K; k0 += 64) {
#pragma unroll
    for (int i = 0; i < 4; ++i) {
      int r = wid * 32 + i * 8;
      const f16* src =
          (k0 < kspl) ? A + (size_t)(row0 + r + l8) * lda + k0 + lx
                      : A2 + (size_t)(row0 + r + l8) * lda2 + (k0 - kspl) + lx;
      gld_lds16(src, &As[r * 64]);
    }
#pragma unroll
    for (int i = 0; i < BI; ++i) {
      int r = wid * (BN / 4) + i * 8;
      gld_lds16(BT + (size_t)(col0 + r + l8) * ldb + k0 + lx, &Bs[r * 64]);
    }
    __syncthreads();
#pragma unroll
    for (int ks = 0; ks < 2; ++ks) {
      f16x8 af[4], bf[FN];
#pragma unroll
      for (int m = 0; m < 4; ++m)
        af[m] = *(const f16x8*)&As[((wm * 64 + m * 16 + (lane & 15)) * 64 +
                                    ks * 32 + (lane >> 4) * 8) ^ sw];
#pragma unroll
      for (int n = 0; n < FN; ++n)
        bf[n] = *(const f16x8*)&Bs[((wn * WN + n * 16 + (lane & 15)) * 64 +
                                    ks * 32 + (lane >> 4) * 8) ^ sw];
#pragma unroll
      for (int m = 0; m < 4; ++m)
#pragma unroll
        for (int n = 0; n < FN; ++n)
          acc[m][n] = __builtin_amdgcn_mfma_f32_16x16x32_f16(af[m], bf[n],
                                                             acc[m][n], 0, 0, 0);
    }
    __syncthreads();
  }

  const int cl = lane & 15, rh4 = (lane >> 4) * 4;
  float* Cfb = Cf + zb * zC;
  f16* Chb = Ch + zb * zC;
  const float* bp = (EPI == 5 && zb == 1) ? bias2 : bias;
#pragma unroll
  for (int m = 0; m < 4; ++m) {
#pragma unroll
    for (int n = 0; n < FN; ++n) {
      int cc = col0 + wn * WN + n * 16 + cl;
      float bv = 0.f;
      if (EPI == 6)
        bv = (cc < 256) ? bias[cc] : bias2[cc - 256];
      else if (bp)
        bv = bp[cc];
#pragma unroll
      for (int q = 0; q < 4; ++q) {
        size_t r = row0 + wm * 64 + m * 16 + rh4 + q;
        float v = acc[m][n][q] + bv;
        if (EPI == 4) {
          v += (float)Xpre[r * 768 + cc];
          float sv = 1.f / (1.f + __expf(-v));
          if (cc < 256)
            Xrh[r * 256 + cc] = (f16)(sv * X1f[r * 256 + cc]);
          else
            Xu_out[r * 256 + cc - 256] = sv;
        } else {
          if (EPI == 1) v = fmaxf(v, 0.f);
          if (EPI == 5) v = (zb == 0) ? tanhf(v) : 1.f / (1.f + __expf(-v));
          if (EPI == 6)
            v = (cc < 256) ? tanhf(v) : 1.f / (1.f + __expf(-v));
          if (WOUT == 0 || WOUT == 2) Cfb[r * ldc + cc] = v;
          if (WOUT == 1 || WOUT == 2) Chb[r * ldc + cc] = (f16)v;
        }
      }
    }
  }
}

// ---------------------------------------------------------------------------
// sup_agg v3: aggP[kh][t][m][c] partials, 64 rows x 384 cols x K=512.
// grid (32, 4, 4) = 512 blocks.  LDS 56 KB -> 2 blocks/CU.
// ---------------------------------------------------------------------------
__global__ __launch_bounds__(256) void sup_agg(
    const float* __restrict__ sup, const f16* __restrict__ edmT,
    f16* __restrict__ aggP) {
  __shared__ alignas(16) f16 As[64 * 64];
  __shared__ alignas(16) f16 Bs[384 * 64];
  const int tid = threadIdx.x;
  const int lane = tid & 63, wid = tid >> 6;
  const int m0 = blockIdx.x * 64, kh = blockIdx.y, t = blockIdx.z;
  const int l8 = lane >> 3;
  const int lx = ((lane & 7) ^ l8) * 8;
  const int sw = (lane & 7) * 8;
  const int cl = lane & 15, hi = lane >> 4;
  const int wm = wid >> 1, wn = wid & 1;
  const float* supT = sup + (size_t)t * NN * NN;
  const f16* edmTt = edmT + (size_t)t * G_IN * NN;

  f32x4 acc[2][12];
#pragma unroll
  for (int m = 0; m < 2; ++m)
#pragma unroll
    for (int n = 0; n < 12; ++n) acc[m][n] = (f32x4){0.f, 0.f, 0.f, 0.f};

  const int ar = tid >> 2;              // 0..63 rows
  const int g0 = (tid & 3) * 2;         // source granule pair
  const int kbeg = kh * 512;

  for (int k0 = kbeg; k0 < kbeg + 512; k0 += 64) {
    const float* ap = supT + (size_t)(m0 + ar) * NN + k0 + (tid & 3) * 16;
    float4 f0 = *(const float4*)ap;
    float4 f1 = *(const float4*)(ap + 4);
    float4 f2 = *(const float4*)(ap + 8);
    float4 f3 = *(const float4*)(ap + 12);
    f16x8 hv0 = {(f16)f0.x, (f16)f0.y, (f16)f0.z, (f16)f0.w,
                 (f16)f1.x, (f16)f1.y, (f16)f1.z, (f16)f1.w};
    f16x8 hv1 = {(f16)f2.x, (f16)f2.y, (f16)f2.z, (f16)f2.w,
                 (f16)f3.x, (f16)f3.y, (f16)f3.z, (f16)f3.w};
    *(f16x8*)&As[ar * 64 + ((g0 ^ (ar & 7)) * 8)] = hv0;
    *(f16x8*)&As[ar * 64 + (((g0 + 1) ^ (ar & 7)) * 8)] = hv1;
#pragma unroll
    for (int i = 0; i < 12; ++i) {
      int rn = wid * 96 + i * 8;
      gld_lds16(edmTt + (size_t)(rn + l8) * NN + k0 + lx, &Bs[rn * 64]);
    }
    __syncthreads();
#pragma unroll
    for (int ks = 0; ks < 2; ++ks) {
      f16x8 af[2], bf[12];
#pragma unroll
      for (int m = 0; m < 2; ++m)
        af[m] = *(const f16x8*)&As[((wm * 32 + m * 16 + cl) * 64 + ks * 32 +
                                    hi * 8) ^ sw];
#pragma unroll
      for (int n = 0; n < 12; ++n)
        bf[n] = *(const f16x8*)&Bs[((wn * 192 + n * 16 + cl) * 64 + ks * 32 +
                                    hi * 8) ^ sw];
#pragma unroll
      for (int m = 0; m < 2; ++m)
#pragma unroll
        for (int n = 0; n < 12; ++n)
          acc[m][n] = __builtin_amdgcn_mfma_f32_16x16x32_f16(af[m], bf[n],
                                                             acc[m][n], 0, 0, 0);
    }
    __syncthreads();
  }

  f16* dst = aggP + (size_t)kh * (4L * NN * G_IN) +
             ((size_t)t * NN + m0) * G_IN;
#pragma unroll
  for (int m = 0; m < 2; ++m)
#pragma unroll
    for (int n = 0; n < 12; ++n)
#pragma unroll
      for (int q = 0; q < 4; ++q)
        dst[(size_t)(wm * 32 + m * 16 + hi * 4 + q) * G_IN + wn * 192 +
            n * 16 + cl] = (f16)acc[m][n][q];
}

// ---------------------------------------------------------------------------
// gnn_l2: g16[r] = l2norm(relu((sum of 4 aggP partials) @ Wgnn + b))
// 32 rows/block, grid 256.
// ---------------------------------------------------------------------------
__global__ __launch_bounds__(256) void gnn_l2(
    const f16* __restrict__ aggP, const f16* __restrict__ WgnnT,
    const float* __restrict__ bgnn, f16* __restrict__ g16) {
  __shared__ alignas(16) f16 As[32 * 64];
  __shared__ alignas(16) f16 Bs[256 * 64];
  __shared__ float red[4][32];
  const int tid = threadIdx.x;
  const int lane = tid & 63, wid = tid >> 6;
  const int m0 = blockIdx.x * 32;
  const int l8 = lane >> 3;
  const int lx = ((lane & 7) ^ l8) * 8;
  const int sw = (lane & 7) * 8;
  const int cl = lane & 15, hi = lane >> 4;
  const long PS = 4L * NN * G_IN;

  f32x4 acc[2][4];
#pragma unroll
  for (int m = 0; m < 2; ++m)
#pragma unroll
    for (int n = 0; n < 4; ++n) acc[m][n] = (f32x4){0.f, 0.f, 0.f, 0.f};

  const int ar = tid >> 3;
  const int acw = ((tid & 7) ^ (ar & 7)) * 8;

  for (int k0 = 0; k0 < G_IN; k0 += 64) {
    size_t gi = (size_t)(m0 + ar) * G_IN + k0 + ((tid & 7) * 8);
    f16x8 a0 = *(const f16x8*)(aggP + gi);
    f16x8 a1 = *(const f16x8*)(aggP + PS + gi);
    f16x8 a2 = *(const f16x8*)(aggP + 2 * PS + gi);
    f16x8 a3 = *(const f16x8*)(aggP + 3 * PS + gi);
    f16x8 s;
#pragma unroll
    for (int e = 0; e < 8; ++e)
      s[e] = (f16)((float)a0[e] + (float)a1[e] + (float)a2[e] + (float)a3[e]);
    *(f16x8*)&As[ar * 64 + acw] = s;
#pragma unroll
    for (int i = 0; i < 8; ++i) {
      int rn = wid * 64 + i * 8;
      gld_lds16(WgnnT + (size_t)(rn + l8) * G_IN + k0 + lx, &Bs[rn * 64]);
    }
    __syncthreads();
#pragma unroll
    for (int ks = 0; ks < 2; ++ks) {
      f16x8 af[2], bf[4];
#pragma unroll
      for (int m = 0; m < 2; ++m)
        af[m] = *(const f16x8*)&As[((m * 16 + cl) * 64 + ks * 32 + hi * 8) ^ sw];
#pragma unroll
      for (int n = 0; n < 4; ++n)
        bf[n] = *(const f16x8*)&Bs[((wid * 64 + n * 16 + cl) * 64 + ks * 32 +
                                    hi * 8) ^ sw];
#pragma unroll
      for (int m = 0; m < 2; ++m)
#pragma unroll
        for (int n = 0; n < 4; ++n)
          acc[m][n] = __builtin_amdgcn_mfma_f32_16x16x32_f16(af[m], bf[n],
                                                             acc[m][n], 0, 0, 0);
    }
    __syncthreads();
  }

#pragma unroll
  for (int m = 0; m < 2; ++m)
#pragma unroll
    for (int n = 0; n < 4; ++n) {
      float bv = bgnn[wid * 64 + n * 16 + cl];
#pragma unroll
      for (int q = 0; q < 4; ++q)
        acc[m][n][q] = fmaxf(acc[m][n][q] + bv, 0.f);
    }
#pragma unroll
  for (int m = 0; m < 2; ++m)
#pragma unroll
    for (int q = 0; q < 4; ++q) {
      float ss = 0.f;
#pragma unroll
      for (int n = 0; n < 4; ++n) ss += acc[m][n][q] * acc[m][n][q];
#pragma unroll
      for (int msk = 1; msk < 16; msk <<= 1) ss += __shfl_xor(ss, msk);
      if (cl == 0) red[wid][m * 16 + hi * 4 + q] = ss;
    }
  __syncthreads();
#pragma unroll
  for (int m = 0; m < 2; ++m)
#pragma unroll
    for (int q = 0; q < 4; ++q) {
      int row = m * 16 + hi * 4 + q;
      float tot = red[0][row] + red[1][row] + red[2][row] + red[3][row];
      float inv = 1.f / fmaxf(sqrtf(tot), 1e-12f);
#pragma unroll
      for (int n = 0; n < 4; ++n)
        g16[(size_t)(m0 + row) * 256 + wid * 64 + n * 16 + cl] =
            (f16)(acc[m][n][q] * inv);
    }
}

// --- sum 4 K-split partials -> h f32 + f16 -----------------------------------
__global__ __launch_bounds__(256) void hsum4(const float* __restrict__ hP,
                                             float* __restrict__ hf,
                                             f16* __restrict__ h16) {
  long i = ((long)blockIdx.x * 256 + threadIdx.x) * 4;
  float4 a = *(const float4*)(hP + i);
  float4 b = *(const float4*)(hP + 524288 + i);
  float4 c = *(const float4*)(hP + 1048576 + i);
  float4 d = *(const float4*)(hP + 1572864 + i);
  float4 s = {a.x + b.x + c.x + d.x, a.y + b.y + c.y + d.y,
              a.z + b.z + c.z + d.z, a.w + b.w + c.w + d.w};
  *(float4*)(hf + i) = s;
  f16x4 o = {(f16)s.x, (f16)s.y, (f16)s.z, (f16)s.w};
  *(f16x4*)(h16 + i) = o;
}

// --- t=0 shortcut: rnn0 = sigmoid(Xg_u+bg)*tanh(Xc+bc), transposed ----------
__global__ __launch_bounds__(256) void rnn0_t(const f16* __restrict__ Xgc,
                                              const float* __restrict__ bg,
                                              const float* __restrict__ bc,
                                              f16* __restrict__ rnnT) {
  __shared__ float tile[32][33];
  int n0 = blockIdx.x * 32, k0 = blockIdx.y * 32;
  int tx = threadIdx.x & 31, ty = threadIdx.x >> 5;
#pragma unroll
  for (int i = 0; i < 32; i += 8) {
    int n = n0 + ty + i, k = k0 + tx;
    float u = 1.f / (1.f + __expf(-((float)Xgc[(size_t)n * 768 + 256 + k] +
                                    bg[256 + k])));
    float c = tanhf((float)Xgc[(size_t)n * 768 + 512 + k] + bc[k]);
    tile[ty + i][tx] = u * c;
  }
  __syncthreads();
#pragma unroll
  for (int i = 0; i < 32; i += 8)
    rnnT[(size_t)(k0 + ty + i) * NN + n0 + tx] = (f16)tile[tx][ty + i];
}

// ---------------------------------------------------------------------------
// Candidate GEMM (K=256) + GRU mix + transposed write.
// c = tanh(rh@Wch + Xc + bc); rnn = (1-u)h + u*c -> rnnT.
// ---------------------------------------------------------------------------
__global__ __launch_bounds__(256) void cgemm_rnnT(
    const f16* __restrict__ A, const f16* __restrict__ BT,
    const float* __restrict__ bias, const f16* __restrict__ Xc,
    const float* __restrict__ hf, const float* __restrict__ ubuf,
    f16* __restrict__ rnnT) {
  __shared__ alignas(16) f16 As[128 * 64];
  __shared__ alignas(16) f16 Bs[64 * 64];
  __shared__ alignas(16) f16 tileT[64 * 136];
  const int tid = threadIdx.x;
  const int lane = tid & 63, wid = tid >> 6;
  const int wm = wid >> 1, wn = wid & 1;
  const int row0 = blockIdx.y * 128, col0 = blockIdx.x * 64;
  const int l8 = lane >> 3;
  const int lx = ((lane & 7) ^ l8) * 8;
  const int sw = (lane & 7) * 8;

  f32x4 acc[4][2];
#pragma unroll
  for (int m = 0; m < 4; ++m)
#pragma unroll
    for (int n = 0; n < 2; ++n) acc[m][n] = (f32x4){0.f, 0.f, 0.f, 0.f};

  for (int k0 = 0; k0 < 256; k0 += 64) {
#pragma unroll
    for (int i = 0; i < 4; ++i) {
      int r = wid * 32 + i * 8;
      gld_lds16(A + (size_t)(row0 + r + l8) * 256 + k0 + lx, &As[r * 64]);
    }
#pragma unroll
    for (int i = 0; i < 2; ++i) {
      int r = wid * 16 + i * 8;
      gld_lds16(BT + (size_t)(col0 + r + l8) * 256 + k0 + lx, &Bs[r * 64]);
    }
    __syncthreads();
#pragma unroll
    for (int ks = 0; ks < 2; ++ks) {
      f16x8 af[4], bf[2];
#pragma unroll
      for (int m = 0; m < 4; ++m)
        af[m] = *(const f16x8*)&As[((wm * 64 + m * 16 + (lane & 15)) * 64 +
                                    ks * 32 + (lane >> 4) * 8) ^ sw];
#pragma unroll
      for (int n = 0; n < 2; ++n)
        bf[n] = *(const f16x8*)&Bs[((wn * 32 + n * 16 + (lane & 15)) * 64 +
                                    ks * 32 + (lane >> 4) * 8) ^ sw];
#pragma unroll
      for (int m = 0; m < 4; ++m)
#pragma unroll
        for (int n = 0; n < 2; ++n)
          acc[m][n] = __builtin_amdgcn_mfma_f32_16x16x32_f16(af[m], bf[n],
                                                             acc[m][n], 0, 0, 0);
    }
    __syncthreads();
  }

  const int cl = lane & 15, rh4 = (lane >> 4) * 4;
#pragma unroll
  for (int m = 0; m < 4; ++m) {
#pragma unroll
    for (int n = 0; n < 2; ++n) {
      int ccl = wn * 32 + n * 16 + cl;
      int cc = col0 + ccl;
      float bv = bias[cc];
#pragma unroll
      for (int q = 0; q < 4; ++q) {
        int rl = wm * 64 + m * 16 + rh4 + q;
        size_t r = row0 + rl;
        float c = tanhf(acc[m][n][q] + bv + (float)Xc[r * 768 + cc]);
        float u = ubuf[r * 256 + cc];
        float h = hf[r * 256 + cc];
        tileT[ccl * 136 + rl] = (f16)((1.f - u) * h + u * c);
      }
    }
  }
  __syncthreads();
#pragma unroll
  for (int i = 0; i < 4; ++i) {
    int chunk = i * 256 + tid;
    int rr = chunk >> 4, seg = (chunk & 15) * 8;
    *(f16x8*)&rnnT[(size_t)(col0 + rr) * NN + row0 + seg] =
        *(const f16x8*)&tileT[rr * 136 + seg];
  }
}

// ---------------------------------------------------------------------------
// Fused P/Q/decode
// ---------------------------------------------------------------------------
__global__ __launch_bounds__(256) void pq_decode(
    const f16* __restrict__ emb, const f16* __restrict__ scal,
    const float* __restrict__ sq, float* __restrict__ out) {
  __shared__ alignas(16) f16 EA[128 * 64], EB[128 * 64], SA[128 * 64],
      SB[128 * 64];
  const int tid = threadIdx.x;
  const int lane = tid & 63, wid = tid >> 6;
  const int wm = wid >> 1, wn = wid & 1;
  const int row0 = blockIdx.y * 128, col0 = blockIdx.x * 128;
  const int l8 = lane >> 3;
  const int lx = ((lane & 7) ^ l8) * 8;
  const int sw = (lane & 7) * 8;
#pragma unroll
  for (int i = 0; i < 2; ++i) {
    int r = wid * 16 + i * 8;
    gld_lds16(emb + (size_t)(row0 + r + l8) * 64 + lx, &EA[r * 64]);
    gld_lds16(emb + (size_t)(col0 + r + l8) * 64 + lx, &EB[r * 64]);
    gld_lds16(scal + (size_t)(row0 + r + l8) * 64 + lx, &SA[r * 64]);
    gld_lds16(scal + (size_t)(col0 + r + l8) * 64 + lx, &SB[r * 64]);
    int r2 = r + 64;
    gld_lds16(emb + (size_t)(row0 + r2 + l8) * 64 + lx, &EA[r2 * 64]);
    gld_lds16(emb + (size_t)(col0 + r2 + l8) * 64 + lx, &EB[r2 * 64]);
    gld_lds16(scal + (size_t)(row0 + r2 + l8) * 64 + lx, &SA[r2 * 64]);
    gld_lds16(scal + (size_t)(col0 + r2 + l8) * 64 + lx, &SB[r2 * 64]);
  }
  __syncthreads();
  f32x4 accP[4][4], accQ[4][4];
#pragma unroll
  for (int m = 0; m < 4; ++m)
#pragma unroll
    for (int n = 0; n < 4; ++n) {
      accP[m][n] = (f32x4){0.f, 0.f, 0.f, 0.f};
      accQ[m][n] = (f32x4){0.f, 0.f, 0.f, 0.f};
    }
#pragma unroll
  for (int ks = 0; ks < 2; ++ks) {
    f16x8 af[4], bf[4];
#pragma unroll
    for (int m = 0; m < 4; ++m)
      af[m] = *(const f16x8*)&EA[((wm * 64 + m * 16 + (lane & 15)) * 64 +
                                  ks * 32 + (lane >> 4) * 8) ^ sw];
#pragma unroll
    for (int n = 0; n < 4; ++n)
      bf[n] = *(const f16x8*)&EB[((wn * 64 + n * 16 + (lane & 15)) * 64 +
                                  ks * 32 + (lane >> 4) * 8) ^ sw];
#pragma unroll
    for (int m = 0; m < 4; ++m)
#pragma unroll
      for (int n = 0; n < 4; ++n)
        accP[m][n] = __builtin_amdgcn_mfma_f32_16x16x32_f16(af[m], bf[n],
                                                            accP[m][n], 0, 0, 0);
#pragma unroll
    for (int m = 0; m < 4; ++m)
      af[m] = *(const f16x8*)&SA[((wm * 64 + m * 16 + (lane & 15)) * 64 +
                                  ks * 32 + (lane >> 4) * 8) ^ sw];
#pragma unroll
    for (int n = 0; n < 4; ++n)
      bf[n] = *(const f16x8*)&SB[((wn * 64 + n * 16 + (lane & 15)) * 64 +
                                  ks * 32 + (lane >> 4) * 8) ^ sw];
#pragma unroll
    for (int m = 0; m < 4; ++m)
#pragma unroll
      for (int n = 0; n < 4; ++n)
        accQ[m][n] = __builtin_amdgcn_mfma_f32_16x16x32_f16(af[m], bf[n],
                                                            accQ[m][n], 0, 0, 0);
  }
  const int cl = lane & 15, rh4 = (lane >> 4) * 4;
#pragma unroll
  for (int m = 0; m < 4; ++m) {
#pragma unroll
    for (int n = 0; n < 4; ++n) {
      int c = col0 + wn * 64 + n * 16 + cl;
      float sqc = sq[c];
#pragma unroll
      for (int q = 0; q < 4; ++q) {
        size_t r = row0 + wm * 64 + m * 16 + rh4 + q;
        float dist = -(sq[r] + sqc - 2.f * accP[m][n][q]);
        out[r * NN + c] = 1.f + tanhf(dist * accQ[m][n][q]);
      }
    }
  }
}

// --- fused transpose+convert of the weight matrices --------------------------
struct MT {
  const float* src[11];
  f16* dst[11];
  int K[11], N[11], st[11], ts[12];
};
__global__ __launch_bounds__(256) void multi_transp(MT mt) {
  __shared__ float tile[32][33];
  int b = blockIdx.x, w = 0;
  while (b >= mt.ts[w + 1]) ++w;
  int lt = b - mt.ts[w];
  int K = mt.K[w], N = mt.N[w];
  int tk = lt % (K >> 5), tn = lt / (K >> 5);
  int k0 = tk * 32, n0 = tn * 32;
  int tx = threadIdx.x & 31, ty = threadIdx.x >> 5;
  const float* src = mt.src[w];
#pragma unroll
  for (int i = 0; i < 32; i += 8)
    tile[ty + i][tx] = src[(size_t)(k0 + ty + i) * N + n0 + tx];
  __syncthreads();
  f16* dst = mt.dst[w];
  int st = mt.st[w];
#pragma unroll
  for (int i = 0; i < 32; i += 8)
    dst[(size_t)(n0 + ty + i) * st + k0 + tx] = (f16)tile[tx][ty + i];
}

// --- fused edmT builder: transpose fem16 (f16) + noise (f32) -----------------
__global__ __launch_bounds__(256) void edm_t(const f16* __restrict__ fem16,
                                             const float* __restrict__ noise,
                                             f16* __restrict__ edmT) {
  __shared__ float tile[32][33];
  int bx = blockIdx.x, r0 = blockIdx.y * 32, t = blockIdx.z;
  int tx = threadIdx.x & 31, ty = threadIdx.x >> 5;
  f16* dstT = edmT + (size_t)t * G_IN * NN;
  if (bx < 8) {
    int c0 = bx * 32;
    const f16* src = fem16 + (size_t)t * NN * HF;
#pragma unroll
    for (int i = 0; i < 32; i += 8)
      tile[ty + i][tx] = (float)src[(size_t)(r0 + ty + i) * HF + c0 + tx];
    __syncthreads();
#pragma unroll
    for (int i = 0; i < 32; i += 8)
      dstT[(size_t)(c0 + ty + i) * NN + r0 + tx] = (f16)tile[tx][ty + i];
  } else {
    int c0 = (bx - 8) * 32;
    const float* src = noise + (size_t)t * NN * DZ;
#pragma unroll
    for (int i = 0; i < 32; i += 8)
      tile[ty + i][tx] = src[(size_t)(r0 + ty + i) * DZ + c0 + tx];
    __syncthreads();
#pragma unroll
    for (int i = 0; i < 32; i += 8)
      dstT[(size_t)(HF + c0 + ty + i) * NN + r0 + tx] = (f16)tile[tx][ty + i];
  }
}

// --- f32 -> fp16 convert -----------------------------------------------------
__global__ __launch_bounds__(256) void cvt_h(const float* __restrict__ in,
                                             f16* __restrict__ out) {
  long i = ((long)blockIdx.x * 256 + threadIdx.x) * 4;
  float4 v = *(const float4*)(in + i);
  f16x4 o = {(f16)v.x, (f16)v.y, (f16)v.z, (f16)v.w};
  *(f16x4*)(out + i) = o;
}

// --- row softmax + mix with align -> fp16 (paired batch) ---------------------
__global__ __launch_bounds__(256) void softmax_mix(
    const float* __restrict__ S, const float* __restrict__ Al,
    const float* __restrict__ lam_ptr, f16* __restrict__ Mh) {
  const int tid = threadIdx.x;
  const float4* s4 = (const float4*)(S + (long)blockIdx.x * 2048);
  float4 a = s4[tid], b = s4[tid + 256];
  float m = fmaxf(fmaxf(fmaxf(a.x, a.y), fmaxf(a.z, a.w)),
                  fmaxf(fmaxf(b.x, b.y), fmaxf(b.z, b.w)));
  __shared__ float red[4];
  float w = wave_max(m);
  if ((tid & 63) == 0) red[tid >> 6] = w;
  __syncthreads();
  m = fmaxf(fmaxf(red[0], red[1]), fmaxf(red[2], red[3]));
  __syncthreads();
  a.x = __expf(a.x - m); a.y = __expf(a.y - m);
  a.z = __expf(a.z - m); a.w = __expf(a.w - m);
  b.x = __expf(b.x - m); b.y = __expf(b.y - m);
  b.z = __expf(b.z - m); b.w = __expf(b.w - m);
  float s = a.x + a.y + a.z + a.w + b.x + b.y + b.z + b.w;
  w = wave_sum(s);
  if ((tid & 63) == 0) red[tid >> 6] = w;
  __syncthreads();
  float inv = 1.f / (red[0] + red[1] + red[2] + red[3]);
  float lam = lam_ptr[0], oml = 1.f - lam;
  const float4* al4 = (const float4*)(Al + (long)blockIdx.x * 2048);
  float4 x = al4[tid], y = al4[tid + 256];
  f16x4 o0 = {(f16)(lam * x.x + oml * a.x * inv),
              (f16)(lam * x.y + oml * a.y * inv),
              (f16)(lam * x.z + oml * a.z * inv),
              (f16)(lam * x.w + oml * a.w * inv)};
  f16x4 o1 = {(f16)(lam * y.x + oml * b.x * inv),
              (f16)(lam * y.y + oml * b.y * inv),
              (f16)(lam * y.z + oml * b.z * inv),
              (f16)(lam * y.w + oml * b.w * inv)};
  f16x4* out4 = (f16x4*)(Mh + (long)blockIdx.x * 2048);
  out4[tid] = o0;
  out4[tid + 256] = o1;
}

// --- column L2 norms of emb0 [N,64] ------------------------------------------
__global__ __launch_bounds__(256) void col_l2norm64(
    const float* __restrict__ x, float* __restrict__ cn) {
  int c = blockIdx.x;
  float ss = 0.f;
  for (int r = threadIdx.x; r < NN; r += 256) {
    float v = x[(long)r * 64 + c];
    ss += v * v;
  }
  __shared__ float red[4];
  float w = wave_sum(ss);
  if ((threadIdx.x & 63) == 0) red[threadIdx.x >> 6] = w;
  __syncthreads();
  if (threadIdx.x == 0)
    cn[c] = fmaxf(sqrtf(red[0] + red[1] + red[2] + red[3]), 1e-12f);
}

// --- emb16 = emb0/cn ; sq[i] = row sumsq -------------------------------------
__global__ void norm_sq64h(const float* __restrict__ x,
                           const float* __restrict__ cn,
                           f16* __restrict__ emb16, float* __restrict__ sq) {
  int i = blockIdx.x, j = threadIdx.x;
  float e = x[(long)i * 64 + j] / cn[j];
  emb16[(long)i * 64 + j] = (f16)e;
  float s = wave_sum(e * e);
  if (j == 0) sq[i] = s;
}

// ---------------------------------------------------------------------------
extern "C" void kernel_launch(void* const* d_in, const int* in_sizes, int n_in,
                              void* d_out, int out_size, void* d_ws,
                              size_t ws_size, hipStream_t stream) {
  (void)in_sizes; (void)n_in; (void)out_size; (void)ws_size;
  const float* sup    = (const float*)d_in[0];
  const float* feat   = (const float*)d_in[1];
  const float* noise  = (const float*)d_in[2];
  const float* align  = (const float*)d_in[3];
  const float* lambd  = (const float*)d_in[4];
  const float* W_fem  = (const float*)d_in[5];
  const float* b_fem  = (const float*)d_in[6];
  const float* W_gnn  = (const float*)d_in[7];
  const float* b_gnn  = (const float*)d_in[8];
  const float* Wg_x   = (const float*)d_in[9];
  const float* Wg_h   = (const float*)d_in[10];
  const float* bg     = (const float*)d_in[11];
  const float* Wc_x   = (const float*)d_in[12];
  const float* Wc_h   = (const float*)d_in[13];
  const float* bc     = (const float*)d_in[14];
  const float* W_att  = (const float*)d_in[15];
  const float* b_att  = (const float*)d_in[16];
  const float* W_emb1 = (const float*)d_in[17];
  const float* b_emb1 = (const float*)d_in[18];
  const float* W_emb2 = (const float*)d_in[19];
  const float* b_emb2 = (const float*)d_in[20];
  const float* W_scal1= (const float*)d_in[21];
  const float* b_scal1= (const float*)d_in[22];
  const float* W_scal2= (const float*)d_in[23];
  const float* b_scal2= (const float*)d_in[24];

  char* wsb = (char*)d_ws;
  size_t po = 0;
  auto P = [&](size_t bytes) {
    size_t r = po;
    po += (bytes + 255) & ~(size_t)255;
    return r;
  };
  f16* fem16  = (f16*)(wsb + P(5L * NN * HF * 2));
  f16* fm16   = (f16*)(wsb + P(5L * NN * HH * 2));
  f16* g16    = (f16*)(wsb + P(4L * NN * HH * 2));
  f16* WT     = (f16*)(wsb + P(884736L * 2));
  f16* Xgc16  = (f16*)(wsb + P(4L * NN * 768 * 2));
  float* hA   = (float*)(wsb + P((long)NN * HH * 4));
  float* hB   = (float*)(wsb + P((long)NN * HH * 4));
  f16* h16A   = (f16*)(wsb + P((long)NN * HH * 2));
  f16* h16B   = (f16*)(wsb + P((long)NN * HH * 2));
  float* ubuf = (float*)(wsb + P((long)NN * HH * 4));
  f16* rh16   = (f16*)(wsb + P((long)NN * HH * 2));
  f16* rnnT16 = (f16*)(wsb + P((long)NN * HH * 2));
  float* hP   = (float*)(wsb + P(4L * NN * HH * 4));
  f16* M16_2  = (f16*)(wsb + P(2L * NN * NN * 2));
  f16* e1s1   = (f16*)(wsb + P((long)NN * 512 * 2));
  float* embscF = (float*)(wsb + P(2L * NN * E2D * 4));
  f16* embsc16  = (f16*)(wsb + P(2L * NN * E2D * 2));
  f16* emb16  = (f16*)(wsb + P((long)NN * E2D * 2));
  float* cn   = (float*)(wsb + P(64 * 4));
  float* sq   = (float*)(wsb + P(NN * 4));
  // arena: feat16 | edmT | aggP live early; Sbuf2 aliases after gnn_l2
  size_t arena = P(34078720);
  f16* feat16 = (f16*)(wsb + arena);
  f16* edmT   = (f16*)(wsb + arena + 2621440);
  f16* aggP   = (f16*)(wsb + arena + 8912896);
  float* Sbuf2 = (float*)(wsb + arena);

  // --- weight transpose table -------------------------------------------------
  f16* W_femT  = WT;                       // 256x128
  f16* W_gnnT  = W_femT + 32768;           // 256x384
  f16* WgxcT   = W_gnnT + 98304;           // 768x256 ([Wgx^T; Wcx^T])
  f16* WghT    = WgxcT + 196608;           // 512x256
  f16* WchT    = WghT + 131072;            // 256x256
  f16* W_attT  = WchT + 65536;             // 256x256
  f16* We1s1T  = W_attT + 65536;           // 512x512 ([Wemb1^T; Wscal1^T])
  f16* Wemb2T  = We1s1T + 262144;          // 64x256
  f16* Wscal2T = Wemb2T + 16384;           // 64x256 (adjacent: zB=16384)

  MT mt;
  const float* wsrc[11] = {W_fem, W_gnn, Wg_x, Wc_x, Wg_h, Wc_h,
                           W_att, W_emb1, W_scal1, W_emb2, W_scal2};
  f16* wdst[11] = {W_femT, W_gnnT, WgxcT, WgxcT + 512 * 256, WghT, WchT,
                   W_attT, We1s1T, We1s1T + 256 * 512, Wemb2T, Wscal2T};
  const int wK[11]  = {128, 384, 256, 256, 256, 256, 256, 512, 512, 256, 256};
  const int wNd[11] = {256, 256, 512, 256, 512, 256, 256, 256, 256, 64, 64};
  const int wSt[11] = {128, 384, 256, 256, 256, 256, 256, 512, 512, 256, 256};
  int tcum = 0;
  for (int i = 0; i < 11; ++i) {
    mt.src[i] = wsrc[i];
    mt.dst[i] = wdst[i];
    mt.K[i] = wK[i];
    mt.N[i] = wNd[i];
    mt.st[i] = wSt[i];
    mt.ts[i] = tcum;
    tcum += (wK[i] >> 5) * (wNd[i] >> 5);
  }
  mt.ts[11] = tcum;

  const f16* NH = nullptr;
  const float* NOF = nullptr;
  float* NF = nullptr;
  f16* NHm = nullptr;

  multi_transp<<<tcum, 256, 0, stream>>>(mt);
  cvt_h<<<(5L * NN * F_IN) / 1024, 256, 0, stream>>>(feat, feat16);

  // FEM: fem16 = relu(feat @ W_fem + b)
  hgemm<1, 64, 1><<<dim3(4, 80, 1), 256, 0, stream>>>(
      feat16, NH, W_femT, b_fem, NOF, NF, fem16, NOF, NHm, NF, NH,
      128, 0, 128, 128, 256, 128, 0, 0, 0);

  // edmT
  edm_t<<<dim3(12, 64, 4), 256, 0, stream>>>(fem16, noise, edmT);

  // sup path
  sup_agg<<<dim3(32, 4, 4), 256, 0, stream>>>(sup, edmT, aggP);
  gnn_l2<<<256, 256, 0, stream>>>(aggP, W_gnnT, b_gnn, g16);

  // fm16 = fem @ W_att + b
  hgemm<0, 64, 1><<<dim3(4, 80, 1), 256, 0, stream>>>(
      fem16, NH, W_attT, b_att, NOF, NF, fm16, NOF, NHm, NF, NH,
      256, 0, 256, 256, 256, 256, 0, 0, 0);

  // Xgc = g16 @ [Wgx | Wcx]  -> [8192 x 768] f16 pre-activations
  hgemm<0, 64, 1><<<dim3(12, 64, 1), 256, 0, stream>>>(
      g16, NH, WgxcT, NOF, NOF, NF, Xgc16, NOF, NHm, NF, NH,
      256, 0, 256, 256, 768, 256, 0, 0, 0);

  float* hs[2] = {hA, hB};
  f16* h16s[2] = {h16A, h16B};

  for (int p = 0; p < 2; ++p) {
    // S pair: S[z] = fm[2p+z+1] @ fm[2p+z]^T
    hgemm<0, 128, 0><<<dim3(16, 16, 2), 256, 0, stream>>>(
        fm16 + (size_t)(2 * p + 1) * NN * HH, NH,
        fm16 + (size_t)(2 * p) * NN * HH, NOF, NOF, Sbuf2, NHm, NOF, NHm, NF,
        NH, 256, 0, 256, 256, 2048, 256, (long)NN * HH, (long)NN * HH,
        (long)NN * NN);
    softmax_mix<<<2 * NN, 256, 0, stream>>>(
        Sbuf2, align + (size_t)(2 * p) * NN * NN, lambd, M16_2);

    for (int tl = 0; tl < 2; ++tl) {
      int t = 2 * p + tl;
      if (t == 0) {
        rnn0_t<<<dim3(64, 8, 1), 256, 0, stream>>>(Xgc16, bg, bc, rnnT16);
      } else {
        const float* hprev = hs[(t - 1) & 1];
        const f16* h16prev = h16s[(t - 1) & 1];
        // gates = sigmoid(h@Wgh + Xg[t] + bg) -> rh16, ubuf
        hgemm<4, 64, 0><<<dim3(8, 16, 1), 256, 0, stream>>>(
            h16prev, NH, WghT, bg, NOF, NF, NHm, hprev, rh16, ubuf,
            Xgc16 + (size_t)t * NN * 768, 256, 0, 256, 256, 512, 256, 0, 0, 0);
        // c = tanh(rh@Wch + Xc[t] + bc); rnn -> rnnT16
        cgemm_rnnT<<<dim3(4, 16, 1), 256, 0, stream>>>(
            rh16, WchT, bc, Xgc16 + (size_t)t * NN * 768 + 512, hprev, ubuf,
            rnnT16);
      }
      // h_{t+1} partials = M16 @ rnn (K-split x4)
      hgemm<0, 64, 0><<<dim3(4, 16, 4), 256, 0, stream>>>(
          M16_2 + (size_t)(t & 1) * NN * NN, NH, rnnT16, NOF, NOF, hP, NHm,
          NOF, NHm, NF, NH, 2048, 0, 2048, 2048, 256, 512, 512, 512, 524288);
      hsum4<<<512, 256, 0, stream>>>(hP, hs[t & 1], h16s[t & 1]);
    }
  }

  // --- EAM tail ---------------------------------------------------------------
  const f16* h16fin = h16s[1];  // t=3 -> slot 1
  // e1s1 = [tanh | sigmoid]([h | fem4] @ [Wemb1 | Wscal1] + b)
  hgemm<6, 64, 1><<<dim3(8, 16, 1), 256, 0, stream>>>(
      h16fin, fem16 + 4L * NN * HF, We1s1T, b_emb1, b_scal1, NF, e1s1, NOF,
      NHm, NF, NH, 256, 256, 256, 512, 512, 512, 0, 0, 0);
  // z=0: emb0 = tanh(e1@Wemb2+b); z=1: scal = sigmoid(s1@Wscal2+b)
  hgemm<5, 64, 2><<<dim3(1, 16, 2), 256, 0, stream>>>(
      e1s1, NH, Wemb2T, b_emb2, b_scal2, embscF, embsc16, NOF, NHm, NF, NH,
      512, 0, 512, 256, 64, 256, 256, 16384, (long)NN * E2D);
  col_l2norm64<<<64, 256, 0, stream>>>(embscF, cn);
  norm_sq64h<<<NN, 64, 0, stream>>>(embscF, cn, emb16, sq);

  pq_decode<<<dim3(16, 16, 1), 256, 0, stream>>>(
      emb16, embsc16 + (size_t)NN * E2D, sq, (float*)d_out);
}